// Round 2
// baseline (248.762 us; speedup 1.0000x reference)
//
#include <hip/hip_runtime.h>
#include <hip/hip_bf16.h>

constexpr int Bn = 8, Hn = 512, Ln = 4096, N2n = 32;
constexpr int NC = 8, Tc = Ln / NC;   // 8 chunks of 512

typedef __attribute__((ext_vector_type(8))) short bf16x8;
typedef __attribute__((ext_vector_type(4))) float f32x4;

typedef void __attribute__((address_space(1))) gvoid;
typedef void __attribute__((address_space(3))) lvoid;

__device__ __forceinline__ unsigned short f2bf(float f) {
  unsigned int u = __float_as_uint(f);
  u += 0x7fffu + ((u >> 16) & 1u);   // RNE
  return (unsigned short)(u >> 16);
}

// ---------------- K0: per-(h,n) recurrence params ----------------
__global__ void prep_params(const float* __restrict__ C, const float* __restrict__ log_dt,
                            const float* __restrict__ log_A_real, const float* __restrict__ A_imag,
                            float4* __restrict__ params, float2* __restrict__ paramsT) {
  int idx = blockIdx.x * 256 + threadIdx.x;
  if (idx >= Hn * N2n) return;
  int h = idx / N2n;
  float dt = expf(log_dt[h]);
  float Ar = -expf(log_A_real[idx]);
  float Ai = A_imag[idx];
  float dr = Ar * dt, di = Ai * dt;
  float er = expf(dr);
  float wr = er * cosf(di), wi = er * sinf(di);
  float e1r = wr - 1.0f, e1i = wi;                 // exp(dtA) - 1
  float den = Ar * Ar + Ai * Ai;
  float tr = (e1r * Ar + e1i * Ai) / den;          // (exp(dtA)-1)/A
  float ti = (e1i * Ar - e1r * Ai) / den;
  float Cr = C[idx * 2 + 0], Ci = C[idx * 2 + 1];
  float c2r = 2.0f * (Cr * tr - Ci * ti);
  float c2i = 2.0f * (Cr * ti + Ci * tr);
  params[idx] = make_float4(wr, wi, c2r, -c2i);    // store -C2i for fma form
  // w^Tc in double for the chunk-level scan
  double a = (double)dr * (double)Tc;
  double bb = (double)di * (double)Tc;
  double ea = exp(a);
  paramsT[idx] = make_float2((float)(ea * cos(bb)), (float)(ea * sin(bb)));
}

// ---------------- K1: W fp32 -> bf16 ----------------
__global__ void conv_w(const float* __restrict__ W, unsigned short* __restrict__ Wb) {
  int i = blockIdx.x * 256 + threadIdx.x;
  if (i < 2 * Hn * Hn) Wb[i] = f2bf(W[i]);
}

#define REC_STEP(UV)                                  \
  { float nsr = fmaf(wr, sr, fmaf(-wi, si, (UV)));    \
    float nsi = fmaf(wi, sr, wr * si);                \
    sr = nsr; si = nsi; }

// ---------------- K2a: chunk-local end states L_c ----------------
// block = 256 thr = 4 waves = 8 units; unit = (b, chunk c, h). Lanes = 32 states.
__global__ __launch_bounds__(256, 4) void s4d_phase1(
    const float* __restrict__ u, const float4* __restrict__ params,
    float2* __restrict__ Lbuf) {
  const int tid = threadIdx.x;
  const int w = tid >> 6, lane = tid & 63;
  const int seq = lane >> 5, n = lane & 31;
  const int g = w * 2 + seq;
  const int blk = blockIdx.x;
  const int b = blk / (NC * 64);
  const int rem = blk % (NC * 64);
  const int c = rem / 64;
  const int hgrp = rem % 64;
  const int h = hgrp * 8 + g;
  const int s = b * Hn + h;
  const float* __restrict__ up = u + (size_t)s * Ln + c * Tc;
  const f32x4* __restrict__ u4 = (const f32x4*)up;
  const float4 p = params[h * N2n + n];
  const float wr = p.x, wi = p.y;
  float sr = 0.f, si = 0.f;

  f32x4 bA[8], bB[8];
#pragma unroll
  for (int k = 0; k < 8; ++k) bA[k] = u4[k];
  for (int tp = 0; tp < Tc / 64; ++tp) {
    const int base = tp * 16;
#pragma unroll
    for (int k = 0; k < 8; ++k) bB[k] = u4[base + 8 + k];
#pragma unroll
    for (int t = 0; t < 32; ++t) REC_STEP(bA[t >> 2][t & 3]);
    if (tp < Tc / 64 - 1) {
#pragma unroll
      for (int k = 0; k < 8; ++k) bA[k] = u4[base + 16 + k];
    }
#pragma unroll
    for (int t = 0; t < 32; ++t) REC_STEP(bB[t >> 2][t & 3]);
  }
  Lbuf[((size_t)s * NC + c) * N2n + n] = make_float2(sr, si);
}

// ---------------- K2b: scan over chunks: Einit[c] = state entering chunk c --------
__global__ void chunk_scan(const float2* __restrict__ Lbuf, const float2* __restrict__ paramsT,
                           float2* __restrict__ Einit) {
  int idx = blockIdx.x * 256 + threadIdx.x;   // (b*H+h)*32 + n, 131072 total
  int n = idx & 31;
  int s = idx >> 5;
  int h = s & (Hn - 1);
  float2 wT = paramsT[h * N2n + n];
  float er = 0.f, ei = 0.f;
  size_t base = ((size_t)s * NC) * N2n + n;
#pragma unroll
  for (int c = 0; c < NC; ++c) {
    Einit[base + (size_t)c * N2n] = make_float2(er, ei);
    float2 Lc = Lbuf[base + (size_t)c * N2n];
    float tr = fmaf(wT.x, er, fmaf(-wT.y, ei, Lc.x));
    float ti = fmaf(wT.y, er, fmaf(wT.x, ei, Lc.y));
    er = tr; ei = ti;
  }
}

// ---------------- K2c: per-chunk outputs + skip + GELU -> gyT[b][l][h] bf16 -------
__global__ __launch_bounds__(256, 4) void s4d_phase2(
    const float* __restrict__ u, const float4* __restrict__ params,
    const float* __restrict__ Dv, const float2* __restrict__ Einit,
    unsigned short* __restrict__ gyT) {
  __shared__ float cbuf[4][2][32][36];       // [wave][seq][t][n], stride 36 for b128 reads
  __shared__ unsigned short tbuf[2][32][8];  // [dbuf][l][h-in-block]

  const int tid = threadIdx.x;
  const int w = tid >> 6, lane = tid & 63;
  const int seq = lane >> 5, n = lane & 31;
  const int g = w * 2 + seq;
  const int blk = blockIdx.x;
  const int b = blk / (NC * 64);
  const int rem = blk % (NC * 64);
  const int c = rem / 64;
  const int hgrp = rem % 64;
  const int h = hgrp * 8 + g;
  const int h0 = hgrp * 8;
  const int s = b * Hn + h;
  const int c0 = c * Tc;
  const float* __restrict__ up = u + (size_t)s * Ln + c0;
  const f32x4* __restrict__ u4 = (const f32x4*)up;
  const float4 p = params[h * N2n + n];
  const float wr = p.x, wi = p.y, c2r = p.z, c2in = p.w;
  const float Dh = Dv[h];
  const float2 e0 = Einit[((size_t)s * NC + c) * N2n + n];
  float sr = e0.x, si = e0.y;

  float* __restrict__ cwp = &cbuf[w][seq][0][n];
  const f32x4* __restrict__ crp4 = (const f32x4*)&cbuf[w][seq][n][0];

#define P2TILE(BUF)                                   \
  _Pragma("unroll")                                   \
  for (int t = 0; t < 32; ++t) {                      \
    REC_STEP(BUF[t >> 2][t & 3]);                     \
    cwp[t * 36] = fmaf(c2r, sr, c2in * si);           \
  }

#define EPILOG(TI)                                                                  \
  {                                                                                 \
    asm volatile("s_waitcnt lgkmcnt(0)" ::: "memory");                              \
    f32x4 a4 = {0.f, 0.f, 0.f, 0.f};                                               \
    _Pragma("unroll")                                                               \
    for (int j = 0; j < 8; ++j) a4 += crp4[j];                                      \
    float acc = (a4[0] + a4[1]) + (a4[2] + a4[3]);                                  \
    float ustage = up[(TI) * 32 + n];                                               \
    float v = fmaf(ustage, Dh, acc);                                                \
    float ge = 0.5f * v * (1.0f + erff(v * 0.70710678118654752f));                  \
    tbuf[(TI) & 1][n][g] = f2bf(ge);                                                \
    __syncthreads();                                                                \
    if (tid < 32) {                                                                 \
      uint4 val = *reinterpret_cast<const uint4*>(&tbuf[(TI) & 1][tid][0]);         \
      *reinterpret_cast<uint4*>(&gyT[((size_t)b * Ln + c0 + (TI) * 32 + tid) * Hn + h0]) = val; \
    }                                                                               \
  }

  f32x4 bA[8], bB[8];
#pragma unroll
  for (int k = 0; k < 8; ++k) bA[k] = u4[k];
  for (int tp = 0; tp < Tc / 64; ++tp) {
    const int ti0 = tp * 2;
    const int base = tp * 16;
#pragma unroll
    for (int k = 0; k < 8; ++k) bB[k] = u4[base + 8 + k];
    P2TILE(bA);
    EPILOG(ti0);
    if (tp < Tc / 64 - 1) {
#pragma unroll
      for (int k = 0; k < 8; ++k) bA[k] = u4[base + 16 + k];
    }
    P2TILE(bB);
    EPILOG(ti0 + 1);
  }
#undef P2TILE
#undef EPILOG
}

// ---------------- K3: dual GEMM (a,g) + bias + GLU ----------------
__global__ __launch_bounds__(256, 2) void s4d_gemm(
    const unsigned short* __restrict__ Wb, const unsigned short* __restrict__ gyT,
    const float* __restrict__ bias, float* __restrict__ out) {
  __shared__ unsigned short As[2][128][64];  // [a/g][m-row][k]
  __shared__ unsigned short Bs[128][64];     // [l-row][k]

  const int tid = threadIdx.x;
  const int wid = tid >> 6, lane = tid & 63;
  const int ntg = blockIdx.x & 255;          // 256 N-tiles (b, l0)
  const int mt = blockIdx.x >> 8;            // 4 M-tiles
  const int b = ntg >> 5;
  const int l0 = (ntg & 31) * 128;
  const int m0 = mt * 128;
  const int wm = wid >> 1, wn = wid & 1;

  f32x4 acc[2][4][4];
#pragma unroll
  for (int a = 0; a < 2; ++a)
#pragma unroll
    for (int i = 0; i < 4; ++i)
#pragma unroll
      for (int j = 0; j < 4; ++j) acc[a][i][j] = (f32x4){0.f, 0.f, 0.f, 0.f};

  const int srow = lane >> 3;          // 0..7 rows per 1KB chunk
  const int sk = (lane & 7) * 8;       // 8 bf16 = 16B per lane

  for (int kt = 0; kt < 8; ++kt) {
    const int k0 = kt * 64;
#pragma unroll
    for (int q = 0; q < 4; ++q) {
      const int r8 = wid * 32 + q * 8;
      const unsigned short* srcA = Wb + ((size_t)(m0 + r8 + srow) * 512 + k0 + sk);
      __builtin_amdgcn_global_load_lds((const gvoid*)srcA, (lvoid*)&As[0][r8][0], 16, 0, 0);
      const unsigned short* srcG = Wb + ((size_t)(Hn + m0 + r8 + srow) * 512 + k0 + sk);
      __builtin_amdgcn_global_load_lds((const gvoid*)srcG, (lvoid*)&As[1][r8][0], 16, 0, 0);
      const unsigned short* srcB = gyT + (((size_t)b * Ln + l0 + r8 + srow) * Hn + k0 + sk);
      __builtin_amdgcn_global_load_lds((const gvoid*)srcB, (lvoid*)&Bs[r8][0], 16, 0, 0);
    }
    asm volatile("s_waitcnt vmcnt(0)" ::: "memory");
    __syncthreads();
#pragma unroll
    for (int kk = 0; kk < 2; ++kk) {
      const int koff = kk * 32 + (lane >> 4) * 8;
      bf16x8 af0[4], af1[4], bfv[4];
#pragma unroll
      for (int mf = 0; mf < 4; ++mf) {
        af0[mf] = *(const bf16x8*)&As[0][wm * 64 + mf * 16 + (lane & 15)][koff];
        af1[mf] = *(const bf16x8*)&As[1][wm * 64 + mf * 16 + (lane & 15)][koff];
      }
#pragma unroll
      for (int nf = 0; nf < 4; ++nf)
        bfv[nf] = *(const bf16x8*)&Bs[wn * 64 + nf * 16 + (lane & 15)][koff];
#pragma unroll
      for (int mf = 0; mf < 4; ++mf)
#pragma unroll
        for (int nf = 0; nf < 4; ++nf) {
          acc[0][mf][nf] = __builtin_amdgcn_mfma_f32_16x16x32_bf16(af0[mf], bfv[nf], acc[0][mf][nf], 0, 0, 0);
          acc[1][mf][nf] = __builtin_amdgcn_mfma_f32_16x16x32_bf16(af1[mf], bfv[nf], acc[1][mf][nf], 0, 0, 0);
        }
    }
    __syncthreads();
  }

  // epilogue: C/D layout col=lane&15, row=(lane>>4)*4+r
  const int col = lane & 15, r0 = (lane >> 4) * 4;
#pragma unroll
  for (int mf = 0; mf < 4; ++mf) {
    const int hbase = m0 + wm * 64 + mf * 16 + r0;
#pragma unroll
    for (int nf = 0; nf < 4; ++nf) {
      const int l = l0 + wn * 64 + nf * 16 + col;
      f32x4 va = acc[0][mf][nf], vg = acc[1][mf][nf];
#pragma unroll
      for (int r = 0; r < 4; ++r) {
        const int hh = hbase + r;
        float av = va[r] + bias[hh];
        float gv = vg[r] + bias[Hn + hh];
        out[((size_t)b * Hn + hh) * Ln + l] = av / (1.0f + expf(-gv));
      }
    }
  }
}

extern "C" void kernel_launch(void* const* d_in, const int* in_sizes, int n_in,
                              void* d_out, int out_size, void* d_ws, size_t ws_size,
                              hipStream_t stream) {
  (void)in_sizes; (void)n_in; (void)out_size; (void)ws_size;
  const float* u     = (const float*)d_in[0];
  const float* C     = (const float*)d_in[1];
  const float* logdt = (const float*)d_in[2];
  const float* logA  = (const float*)d_in[3];
  const float* Aim   = (const float*)d_in[4];
  const float* Dv    = (const float*)d_in[5];
  const float* W     = (const float*)d_in[6];
  const float* bias  = (const float*)d_in[7];
  float* out = (float*)d_out;

  char* ws = (char*)d_ws;
  float4* params      = (float4*)ws;                                   // 256 KB
  float2* paramsT     = (float2*)(ws + (256 << 10));                   // 128 KB
  unsigned short* Wb  = (unsigned short*)(ws + (384 << 10));           // 1 MB
  unsigned short* gyT = (unsigned short*)(ws + (384 << 10) + (1 << 20)); // 32 MB

  // Lbuf / Einit live in d_out (16 MB of 64 MB); fully consumed before the
  // final GEMM overwrites every element of d_out.
  float2* Lbuf  = (float2*)d_out;                         // 8 MB
  float2* Einit = (float2*)((char*)d_out + (8 << 20));    // 8 MB

  hipLaunchKernelGGL(prep_params, dim3(64), dim3(256), 0, stream, C, logdt, logA, Aim, params, paramsT);
  hipLaunchKernelGGL(conv_w, dim3(2048), dim3(256), 0, stream, W, Wb);
  hipLaunchKernelGGL(s4d_phase1, dim3(Bn * NC * 64), dim3(256), 0, stream, u, params, Lbuf);
  hipLaunchKernelGGL(chunk_scan, dim3(Bn * Hn * N2n / 256), dim3(256), 0, stream, Lbuf, paramsT, Einit);
  hipLaunchKernelGGL(s4d_phase2, dim3(Bn * NC * 64), dim3(256), 0, stream, u, params, Dv, Einit, gyT);
  hipLaunchKernelGGL(s4d_gemm, dim3(4 * 256), dim3(256), 0, stream, Wb, gyT, bias, out);
}

// Round 3
// 237.258 us; speedup vs baseline: 1.0485x; 1.0485x over previous
//
#include <hip/hip_runtime.h>
#include <hip/hip_bf16.h>

constexpr int Bn = 8, Hn = 512, Ln = 4096, N2n = 32;
constexpr int NC = 8, Tc = Ln / NC;   // 8 chunks of 512

typedef __attribute__((ext_vector_type(8))) short bf16x8;
typedef __attribute__((ext_vector_type(4))) float f32x4;
typedef __attribute__((ext_vector_type(2))) float f32x2;

typedef void __attribute__((address_space(1))) gvoid;
typedef void __attribute__((address_space(3))) lvoid;

__device__ __forceinline__ unsigned short f2bf(float f) {
  unsigned int u = __float_as_uint(f);
  u += 0x7fffu + ((u >> 16) & 1u);   // RNE
  return (unsigned short)(u >> 16);
}

// ---- packed fp32 helpers (VOP3P) ----
__device__ __forceinline__ f32x2 pk_fma(f32x2 a, f32x2 b, f32x2 c) {
  f32x2 d;
  asm("v_pk_fma_f32 %0, %1, %2, %3" : "=v"(d) : "v"(a), "v"(b), "v"(c));
  return d;
}
// lo = a.lo*s.hi + u.lo ; hi = a.hi*s.lo + u.hi   (swapped-s complex-mul step)
__device__ __forceinline__ f32x2 pk_fma_sw(f32x2 a, f32x2 s, f32x2 u) {
  f32x2 d;
  asm("v_pk_fma_f32 %0, %1, %2, %3 op_sel:[0,1,0] op_sel_hi:[1,0,1]"
      : "=v"(d) : "v"(a), "v"(s), "v"(u));
  return d;
}
__device__ __forceinline__ f32x2 pk_mul(f32x2 a, f32x2 b) {
  f32x2 d;
  asm("v_pk_mul_f32 %0, %1, %2" : "=v"(d) : "v"(a), "v"(b));
  return d;
}

// ---------------- K0: per-(h,n) recurrence params ----------------
__global__ void prep_params(const float* __restrict__ C, const float* __restrict__ log_dt,
                            const float* __restrict__ log_A_real, const float* __restrict__ A_imag,
                            float4* __restrict__ params, float2* __restrict__ paramsT) {
  int idx = blockIdx.x * 256 + threadIdx.x;
  if (idx >= Hn * N2n) return;
  int h = idx / N2n;
  float dt = expf(log_dt[h]);
  float Ar = -expf(log_A_real[idx]);
  float Ai = A_imag[idx];
  float dr = Ar * dt, di = Ai * dt;
  float er = expf(dr);
  float wr = er * cosf(di), wi = er * sinf(di);
  float e1r = wr - 1.0f, e1i = wi;                 // exp(dtA) - 1
  float den = Ar * Ar + Ai * Ai;
  float tr = (e1r * Ar + e1i * Ai) / den;          // (exp(dtA)-1)/A
  float ti = (e1i * Ar - e1r * Ai) / den;
  float Cr = C[idx * 2 + 0], Ci = C[idx * 2 + 1];
  float c2r = 2.0f * (Cr * tr - Ci * ti);
  float c2i = 2.0f * (Cr * ti + Ci * tr);
  params[idx] = make_float4(wr, wi, c2r, -c2i);    // store -C2i for fma form
  // w^Tc in double for the chunk-level scan
  double a = (double)dr * (double)Tc;
  double bb = (double)di * (double)Tc;
  double ea = exp(a);
  paramsT[idx] = make_float2((float)(ea * cos(bb)), (float)(ea * sin(bb)));
}

// ---------------- K1: W fp32 -> bf16 ----------------
__global__ void conv_w(const float* __restrict__ W, unsigned short* __restrict__ Wb) {
  int i = blockIdx.x * 256 + threadIdx.x;
  if (i < 2 * Hn * Hn) Wb[i] = f2bf(W[i]);
}

// ---------------- K2a: chunk-local end states L_c ----------------
// 16 lanes per sequence, 2 states per lane (np, np+16); 4 seqs/wave, 16 seqs/block.
__global__ __launch_bounds__(256, 4) void s4d_phase1(
    const float* __restrict__ u, const float4* __restrict__ params,
    float2* __restrict__ Lbuf) {
  const int tid = threadIdx.x;
  const int w = tid >> 6, lane = tid & 63;
  const int sg = lane >> 4, np = lane & 15;
  const int sgg = w * 4 + sg;
  const int blk = blockIdx.x;
  const int b = blk >> 8;                 // NC*32 = 256 units per batch
  const int rem = blk & 255;
  const int c = rem >> 5, hgrp = rem & 31;
  const int h = hgrp * 16 + sgg;
  const int s = b * Hn + h;
  const f32x4* __restrict__ u4 = (const f32x4*)(u + (size_t)s * Ln + c * Tc);

  const float4 pA = params[h * N2n + np];
  const float4 pB = params[h * N2n + np + 16];
  const f32x2 W1A = {pA.x, pA.x}, W2A = {-pA.y, pA.y};
  const f32x2 W1B = {pB.x, pB.x}, W2B = {-pB.y, pB.y};
  f32x2 SA = {0.f, 0.f}, SB = {0.f, 0.f};
  f32x2 U = {0.f, 0.f};

  f32x4 cur[4], nxt[4];
#pragma unroll
  for (int k = 0; k < 4; ++k) cur[k] = u4[k];
  for (int tile = 0; tile < Tc / 16; ++tile) {
    if (tile < Tc / 16 - 1) {
#pragma unroll
      for (int k = 0; k < 4; ++k) nxt[k] = u4[(tile + 1) * 4 + k];
    }
#pragma unroll
    for (int t = 0; t < 16; ++t) {
      U.x = cur[t >> 2][t & 3];
      SA = pk_fma(W1A, SA, pk_fma_sw(W2A, SA, U));
      SB = pk_fma(W1B, SB, pk_fma_sw(W2B, SB, U));
    }
    if (tile < Tc / 16 - 1) {
#pragma unroll
      for (int k = 0; k < 4; ++k) cur[k] = nxt[k];
    }
  }
  size_t base = ((size_t)s * NC + c) * N2n;
  Lbuf[base + np]      = make_float2(SA.x, SA.y);
  Lbuf[base + np + 16] = make_float2(SB.x, SB.y);
}

// ---------------- K2b: scan over chunks: Einit[c] = state entering chunk c --------
__global__ void chunk_scan(const float2* __restrict__ Lbuf, const float2* __restrict__ paramsT,
                           float2* __restrict__ Einit) {
  int idx = blockIdx.x * 256 + threadIdx.x;   // (b*H+h)*32 + n, 131072 total
  int n = idx & 31;
  int s = idx >> 5;
  int h = s & (Hn - 1);
  float2 wT = paramsT[h * N2n + n];
  float er = 0.f, ei = 0.f;
  size_t base = ((size_t)s * NC) * N2n + n;
#pragma unroll
  for (int c = 0; c < NC; ++c) {
    Einit[base + (size_t)c * N2n] = make_float2(er, ei);
    float2 Lc = Lbuf[base + (size_t)c * N2n];
    float tr = fmaf(wT.x, er, fmaf(-wT.y, ei, Lc.x));
    float ti = fmaf(wT.y, er, fmaf(wT.x, ei, Lc.y));
    er = tr; ei = ti;
  }
}

// ---------------- K2c: per-chunk outputs + skip + GELU -> gyT[b][l][h] bf16 -------
// 2 states/lane, 16 lanes/seq, 4 seqs/wave, 16 seqs/block (h0..h0+15).
__global__ __launch_bounds__(256, 4) void s4d_phase2(
    const float* __restrict__ u, const float4* __restrict__ params,
    const float* __restrict__ Dv, const float2* __restrict__ Einit,
    unsigned short* __restrict__ gyT) {
  __shared__ float cbuf[4][4][16][17];       // [wave][seq][t][np], 17-stride: conflict-free
  __shared__ unsigned int tbuf[2][16][17];   // [dbuf][t][sgg] bf16-in-u32 staging

  const int tid = threadIdx.x;
  const int w = tid >> 6, lane = tid & 63;
  const int sg = lane >> 4, np = lane & 15;
  const int sgg = w * 4 + sg;
  const int blk = blockIdx.x;
  const int b = blk >> 8;
  const int rem = blk & 255;
  const int c = rem >> 5, hgrp = rem & 31;
  const int h = hgrp * 16 + sgg;
  const int h0 = hgrp * 16;
  const int s = b * Hn + h;
  const int c0 = c * Tc;
  const float* __restrict__ up = u + (size_t)s * Ln + c0;
  const f32x4* __restrict__ u4 = (const f32x4*)up;

  const float4 pA = params[h * N2n + np];
  const float4 pB = params[h * N2n + np + 16];
  const f32x2 W1A = {pA.x, pA.x}, W2A = {-pA.y, pA.y}, C2A = {pA.z, pA.w};
  const f32x2 W1B = {pB.x, pB.x}, W2B = {-pB.y, pB.y}, C2B = {pB.z, pB.w};
  const float Dh = Dv[h];
  const float2 e0A = Einit[((size_t)s * NC + c) * N2n + np];
  const float2 e0B = Einit[((size_t)s * NC + c) * N2n + np + 16];
  f32x2 SA = {e0A.x, e0A.y}, SB = {e0B.x, e0B.y};
  f32x2 U = {0.f, 0.f};

  f32x4 cur[4], nxt[4];
#pragma unroll
  for (int k = 0; k < 4; ++k) cur[k] = u4[k];

  for (int tile = 0; tile < Tc / 16; ++tile) {
    if (tile < Tc / 16 - 1) {
#pragma unroll
      for (int k = 0; k < 4; ++k) nxt[k] = u4[(tile + 1) * 4 + k];
    }
#pragma unroll
    for (int t = 0; t < 16; ++t) {
      U.x = cur[t >> 2][t & 3];
      SA = pk_fma(W1A, SA, pk_fma_sw(W2A, SA, U));
      SB = pk_fma(W1B, SB, pk_fma_sw(W2B, SB, U));
      f32x2 P = pk_fma(C2B, SB, pk_mul(C2A, SA));
      cbuf[w][sg][t][np] = P.x + P.y;        // partial over this lane's 2 states
    }
    // reduction: lane handles (seq sg, t=np) — all data written by this wave
    float a0 = 0.f, a1 = 0.f, a2 = 0.f, a3 = 0.f;
#pragma unroll
    for (int j = 0; j < 16; j += 4) {
      a0 += cbuf[w][sg][np][j + 0];
      a1 += cbuf[w][sg][np][j + 1];
      a2 += cbuf[w][sg][np][j + 2];
      a3 += cbuf[w][sg][np][j + 3];
    }
    float acc = (a0 + a1) + (a2 + a3);
    float ustage = up[tile * 16 + np];
    float v = fmaf(ustage, Dh, acc);
    float ge = 0.5f * v * (1.0f + erff(v * 0.70710678118654752f));
    tbuf[tile & 1][np][sgg] = (unsigned int)f2bf(ge);
    __syncthreads();
    if (tid < 64) {  // repack 16 rows x 16 bf16, store 8B per thread
      const int r = tid >> 2, q = tid & 3;
      unsigned int t0 = tbuf[tile & 1][r][q * 4 + 0];
      unsigned int t1 = tbuf[tile & 1][r][q * 4 + 1];
      unsigned int t2 = tbuf[tile & 1][r][q * 4 + 2];
      unsigned int t3 = tbuf[tile & 1][r][q * 4 + 3];
      uint2 pv = make_uint2(t0 | (t1 << 16), t2 | (t3 << 16));
      const int l = c0 + tile * 16 + r;
      *reinterpret_cast<uint2*>(&gyT[((size_t)b * Ln + l) * Hn + h0 + q * 4]) = pv;
    }
    if (tile < Tc / 16 - 1) {
#pragma unroll
      for (int k = 0; k < 4; ++k) cur[k] = nxt[k];
    }
  }
}

// ---------------- K3: dual GEMM (a,g) + bias + GLU ----------------
__global__ __launch_bounds__(256, 2) void s4d_gemm(
    const unsigned short* __restrict__ Wb, const unsigned short* __restrict__ gyT,
    const float* __restrict__ bias, float* __restrict__ out) {
  __shared__ unsigned short As[2][128][64];  // [a/g][m-row][k]
  __shared__ unsigned short Bs[128][64];     // [l-row][k]

  const int tid = threadIdx.x;
  const int wid = tid >> 6, lane = tid & 63;
  const int ntg = blockIdx.x & 255;          // 256 N-tiles (b, l0)
  const int mt = blockIdx.x >> 8;            // 4 M-tiles
  const int b = ntg >> 5;
  const int l0 = (ntg & 31) * 128;
  const int m0 = mt * 128;
  const int wm = wid >> 1, wn = wid & 1;

  f32x4 acc[2][4][4];
#pragma unroll
  for (int a = 0; a < 2; ++a)
#pragma unroll
    for (int i = 0; i < 4; ++i)
#pragma unroll
      for (int j = 0; j < 4; ++j) acc[a][i][j] = (f32x4){0.f, 0.f, 0.f, 0.f};

  const int srow = lane >> 3;          // 0..7 rows per 1KB chunk
  const int sk = (lane & 7) * 8;       // 8 bf16 = 16B per lane

  for (int kt = 0; kt < 8; ++kt) {
    const int k0 = kt * 64;
#pragma unroll
    for (int q = 0; q < 4; ++q) {
      const int r8 = wid * 32 + q * 8;
      const unsigned short* srcA = Wb + ((size_t)(m0 + r8 + srow) * 512 + k0 + sk);
      __builtin_amdgcn_global_load_lds((const gvoid*)srcA, (lvoid*)&As[0][r8][0], 16, 0, 0);
      const unsigned short* srcG = Wb + ((size_t)(Hn + m0 + r8 + srow) * 512 + k0 + sk);
      __builtin_amdgcn_global_load_lds((const gvoid*)srcG, (lvoid*)&As[1][r8][0], 16, 0, 0);
      const unsigned short* srcB = gyT + (((size_t)b * Ln + l0 + r8 + srow) * Hn + k0 + sk);
      __builtin_amdgcn_global_load_lds((const gvoid*)srcB, (lvoid*)&Bs[r8][0], 16, 0, 0);
    }
    asm volatile("s_waitcnt vmcnt(0)" ::: "memory");
    __syncthreads();
#pragma unroll
    for (int kk = 0; kk < 2; ++kk) {
      const int koff = kk * 32 + (lane >> 4) * 8;
      bf16x8 af0[4], af1[4], bfv[4];
#pragma unroll
      for (int mf = 0; mf < 4; ++mf) {
        af0[mf] = *(const bf16x8*)&As[0][wm * 64 + mf * 16 + (lane & 15)][koff];
        af1[mf] = *(const bf16x8*)&As[1][wm * 64 + mf * 16 + (lane & 15)][koff];
      }
#pragma unroll
      for (int nf = 0; nf < 4; ++nf)
        bfv[nf] = *(const bf16x8*)&Bs[wn * 64 + nf * 16 + (lane & 15)][koff];
#pragma unroll
      for (int mf = 0; mf < 4; ++mf)
#pragma unroll
        for (int nf = 0; nf < 4; ++nf) {
          acc[0][mf][nf] = __builtin_amdgcn_mfma_f32_16x16x32_bf16(af0[mf], bfv[nf], acc[0][mf][nf], 0, 0, 0);
          acc[1][mf][nf] = __builtin_amdgcn_mfma_f32_16x16x32_bf16(af1[mf], bfv[nf], acc[1][mf][nf], 0, 0, 0);
        }
    }
    __syncthreads();
  }

  // epilogue: C/D layout col=lane&15, row=(lane>>4)*4+r
  const int col = lane & 15, r0 = (lane >> 4) * 4;
#pragma unroll
  for (int mf = 0; mf < 4; ++mf) {
    const int hbase = m0 + wm * 64 + mf * 16 + r0;
#pragma unroll
    for (int nf = 0; nf < 4; ++nf) {
      const int l = l0 + wn * 64 + nf * 16 + col;
      f32x4 va = acc[0][mf][nf], vg = acc[1][mf][nf];
#pragma unroll
      for (int r = 0; r < 4; ++r) {
        const int hh = hbase + r;
        float av = va[r] + bias[hh];
        float gv = vg[r] + bias[Hn + hh];
        out[((size_t)b * Hn + hh) * Ln + l] = av / (1.0f + expf(-gv));
      }
    }
  }
}

extern "C" void kernel_launch(void* const* d_in, const int* in_sizes, int n_in,
                              void* d_out, int out_size, void* d_ws, size_t ws_size,
                              hipStream_t stream) {
  (void)in_sizes; (void)n_in; (void)out_size; (void)ws_size;
  const float* u     = (const float*)d_in[0];
  const float* C     = (const float*)d_in[1];
  const float* logdt = (const float*)d_in[2];
  const float* logA  = (const float*)d_in[3];
  const float* Aim   = (const float*)d_in[4];
  const float* Dv    = (const float*)d_in[5];
  const float* W     = (const float*)d_in[6];
  const float* bias  = (const float*)d_in[7];
  float* out = (float*)d_out;

  char* ws = (char*)d_ws;
  float4* params      = (float4*)ws;                                   // 256 KB
  float2* paramsT     = (float2*)(ws + (256 << 10));                   // 128 KB
  unsigned short* Wb  = (unsigned short*)(ws + (384 << 10));           // 1 MB
  unsigned short* gyT = (unsigned short*)(ws + (384 << 10) + (1 << 20)); // 32 MB

  // Lbuf / Einit live in d_out (16 MB of 64 MB); fully consumed before the
  // final GEMM overwrites every element of d_out.
  float2* Lbuf  = (float2*)d_out;                         // 8 MB
  float2* Einit = (float2*)((char*)d_out + (8 << 20));    // 8 MB

  hipLaunchKernelGGL(prep_params, dim3(64), dim3(256), 0, stream, C, logdt, logA, Aim, params, paramsT);
  hipLaunchKernelGGL(conv_w, dim3(2048), dim3(256), 0, stream, W, Wb);
  hipLaunchKernelGGL(s4d_phase1, dim3(Bn * NC * (Hn / 16)), dim3(256), 0, stream, u, params, Lbuf);
  hipLaunchKernelGGL(chunk_scan, dim3(Bn * Hn * N2n / 256), dim3(256), 0, stream, Lbuf, paramsT, Einit);
  hipLaunchKernelGGL(s4d_phase2, dim3(Bn * NC * (Hn / 16)), dim3(256), 0, stream, u, params, Dv, Einit, gyT);
  hipLaunchKernelGGL(s4d_gemm, dim3(4 * 256), dim3(256), 0, stream, Wb, gyT, bias, out);
}

// Round 5
// 152.320 us; speedup vs baseline: 1.6332x; 1.5576x over previous
//
#include <hip/hip_runtime.h>
#include <hip/hip_bf16.h>

constexpr int Bn = 8, Hn = 512, Ln = 4096, N2n = 32;

typedef _Float16 f16;
typedef __attribute__((ext_vector_type(8))) _Float16 f16x8;
typedef __attribute__((ext_vector_type(4))) _Float16 f16x4;
typedef __attribute__((ext_vector_type(2))) _Float16 f16x2;
typedef __attribute__((ext_vector_type(4))) float f32x4;

typedef void __attribute__((address_space(1))) gvoid;
typedef void __attribute__((address_space(3))) lvoid;

// ============ K0a: per-h param matrices ============
// V[h][st][j]  (64x64, swizzled chunks): st=2n -> Re(w^(63-j)), 2n+1 -> Im
// A3[h][t][k]  (64x128, swizzled): k<64 = Toeplitz k[t-j] (filled by k_mats2);
//              k>=64: [64+2n]=Re(C2 w^(t+1)), [64+2n+1]=-Im(C2 w^(t+1))
// kg[h][d] fp32, w64[h][n] = w^64 fp32 complex.
// Swizzle: chunk' = chunk ^ (row & 7), chunk = 8 f16 = 16B.
__global__ __launch_bounds__(64) void k_mats1(
    const float* __restrict__ C, const float* __restrict__ log_dt,
    const float* __restrict__ logA, const float* __restrict__ Aim,
    f16* __restrict__ Vg, f16* __restrict__ A3g,
    float* __restrict__ kg, float2* __restrict__ w64g) {
  __shared__ f16 VT[64 * 64];
  __shared__ f16 QT[64 * 64];
  __shared__ float kp[64][33];
  const int h = blockIdx.x, tid = threadIdx.x, n = tid & 31;

  if (tid < 32) {
    const int idx = h * N2n + n;
    float dt = expf(log_dt[h]);
    float Ar = -expf(logA[idx]);
    float Ai = Aim[idx];
    float dr = Ar * dt, di = Ai * dt;
    float er = expf(dr);
    float wr = er * cosf(di), wi = er * sinf(di);
    float den = Ar * Ar + Ai * Ai;
    float e1r = wr - 1.0f, e1i = wi;
    float tr = (e1r * Ar + e1i * Ai) / den;
    float ti = (e1i * Ar - e1r * Ai) / den;
    float Cr = C[idx * 2 + 0], Ci = C[idx * 2 + 1];
    float c2r = 2.0f * (Cr * tr - Ci * ti);
    float c2i = 2.0f * (Cr * ti + Ci * tr);

    float wpr = 1.f, wpi = 0.f;   // w^p
    for (int p = 0; p <= 64; ++p) {
      float cwr = c2r * wpr - c2i * wpi;   // C2 * w^p
      float cwi = c2r * wpi + c2i * wpr;
      if (p < 64) {
        const int j = 63 - p, ch = j >> 3, jo = j & 7;
        const int s0 = 2 * n, s1 = 2 * n + 1;
        VT[s0 * 64 + ((ch ^ (s0 & 7)) * 8) + jo] = (f16)wpr;
        VT[s1 * 64 + ((ch ^ (s1 & 7)) * 8) + jo] = (f16)wpi;
        kp[p][n] = cwr;
      }
      if (p >= 1) {
        const int t = p - 1, c0 = 2 * n;
        const int ch = (c0 >> 3) ^ (t & 7);
        QT[t * 64 + ch * 8 + (c0 & 7)]     = (f16)cwr;
        QT[t * 64 + ch * 8 + (c0 & 7) + 1] = (f16)(-cwi);
      }
      if (p == 64) w64g[h * 32 + n] = make_float2(wpr, wpi);
      float nr = wpr * wr - wpi * wi;
      float ni = wpr * wi + wpi * wr;
      wpr = nr; wpi = ni;
    }
  }
  __syncthreads();
  float s = 0.f;
#pragma unroll
  for (int m = 0; m < 32; ++m) s += kp[tid][m];
  kg[h * 64 + tid] = s;
#pragma unroll
  for (int c = 0; c < 8; ++c)
    *(f16x8*)&Vg[(size_t)h * 4096 + tid * 64 + c * 8] = *(f16x8*)&VT[tid * 64 + c * 8];
#pragma unroll
  for (int c = 0; c < 8; ++c)
    *(f16x8*)&A3g[(size_t)h * 8192 + tid * 128 + 64 + c * 8] = *(f16x8*)&QT[tid * 64 + c * 8];
}

// ============ K0b: fill Toeplitz half of A3 ============
__global__ void k_mats2(const float* __restrict__ kg, f16* __restrict__ A3g) {
  int idx = blockIdx.x * 256 + threadIdx.x;   // 512*64*64
  int h = idx >> 12, t = (idx >> 6) & 63, j = idx & 63;
  float v = (j <= t) ? kg[h * 64 + (t - j)] : 0.f;
  A3g[(size_t)h * 8192 + t * 128 + ((j >> 3) ^ (t & 7)) * 8 + (j & 7)] = (f16)v;
}

// ============ K1: W fp32 -> f16 ============
__global__ void conv_w(const float* __restrict__ W, f16* __restrict__ Wh) {
  int i = blockIdx.x * 256 + threadIdx.x;
  if (i < 2 * Hn * Hn) Wh[i] = (f16)W[i];
}

// ============ K2: L = V·u per (h; cols=(b,blk)) ============
// LE[h][b][blk][st] f16.
__global__ __launch_bounds__(256) void s4d_phase1(
    const float* __restrict__ u, const f16* __restrict__ Vg,
    f16* __restrict__ LEg) {
  __shared__ f16 As[64 * 64];     // V_h, swizzled (global pre-swizzled)
  __shared__ f16 Bs[512 * 64];    // [col=(b,blk)][k=j], swizzled by col
  const int tid = threadIdx.x, wid = tid >> 6, lane = tid & 63;
  const int h = blockIdx.x;

#pragma unroll
  for (int q = 0; q < 2; ++q)
    __builtin_amdgcn_global_load_lds((const gvoid*)(Vg + (size_t)h * 4096 + (q * 256 + tid) * 8),
                                     (lvoid*)&As[(q * 256 + wid * 64) * 8], 16, 0, 0);
#pragma unroll
  for (int i = 0; i < 32; ++i) {
    int e = (i * 256 + tid) * 4;          // 0..32767
    int b = e >> 12, l = e & 4095;
    float4 uv = *(const float4*)(u + ((size_t)(b * Hn + h)) * Ln + l);
    int col = b * 64 + (l >> 6), j = l & 63;
    f16x4 hv = {(f16)uv.x, (f16)uv.y, (f16)uv.z, (f16)uv.w};
    *(f16x4*)&Bs[col * 64 + ((j >> 3) ^ (col & 7)) * 8 + (j & 7)] = hv;
  }
  asm volatile("s_waitcnt vmcnt(0)" ::: "memory");
  __syncthreads();

  f32x4 acc[4][8];
#pragma unroll
  for (int i = 0; i < 4; ++i)
#pragma unroll
    for (int j = 0; j < 8; ++j) acc[i][j] = (f32x4){0.f, 0.f, 0.f, 0.f};

#pragma unroll
  for (int ks = 0; ks < 2; ++ks) {
    const int kc = ks * 4 + (lane >> 4);        // k-chunk 0..7
    f16x8 a[4], bv[8];
#pragma unroll
    for (int mf = 0; mf < 4; ++mf) {
      int row = mf * 16 + (lane & 15);
      a[mf] = *(const f16x8*)&As[row * 64 + ((kc ^ (row & 7)) * 8)];
    }
#pragma unroll
    for (int nf = 0; nf < 8; ++nf) {
      int col = wid * 128 + nf * 16 + (lane & 15);
      bv[nf] = *(const f16x8*)&Bs[col * 64 + ((kc ^ (col & 7)) * 8)];
    }
#pragma unroll
    for (int mf = 0; mf < 4; ++mf)
#pragma unroll
      for (int nf = 0; nf < 8; ++nf)
        acc[mf][nf] = __builtin_amdgcn_mfma_f32_16x16x32_f16(a[mf], bv[nf], acc[mf][nf], 0, 0, 0);
  }
  // store: D row=st=(mf*16+(lane>>4)*4+r), col = wid*128+nf*16+(lane&15)
#pragma unroll
  for (int mf = 0; mf < 4; ++mf) {
    int st0 = mf * 16 + (lane >> 4) * 4;
#pragma unroll
    for (int nf = 0; nf < 8; ++nf) {
      int col = wid * 128 + nf * 16 + (lane & 15);
      f16x4 o = {(f16)acc[mf][nf][0], (f16)acc[mf][nf][1], (f16)acc[mf][nf][2], (f16)acc[mf][nf][3]};
      *(f16x4*)&LEg[(size_t)h * 32768 + col * 64 + st0] = o;
    }
  }
}

// ============ K3: in-place block scan: LE[blk] := E entering blk ============
__global__ void scan64(f16* __restrict__ LEg, const float2* __restrict__ w64g) {
  int idx = blockIdx.x * 256 + threadIdx.x;   // 512*8*32
  int n = idx & 31, b = (idx >> 5) & 7, h = idx >> 8;
  float2 wT = w64g[h * 32 + n];
  float er = 0.f, ei = 0.f;
  size_t base = ((size_t)(h * 8 + b)) * 4096 + 2 * n;
#pragma unroll 4
  for (int blk = 0; blk < 64; ++blk) {
    f16x2 Lv = *(const f16x2*)(LEg + base + blk * 64);
    float Lr = (float)Lv[0], Li = (float)Lv[1];
    *(f16x2*)(LEg + base + blk * 64) = (f16x2){(f16)er, (f16)ei};
    float nr = fmaf(wT.x, er, fmaf(-wT.y, ei, Lr));
    float ni = fmaf(wT.y, er, fmaf(wT.x, ei, Li));
    er = nr; ei = ni;
  }
}

// ============ K4: y = [Tri|Q]·[u;E] + D·u, GELU -> y[b][h][l] f16 ============
__global__ __launch_bounds__(256) void s4d_phase3(
    const float* __restrict__ u, const f16* __restrict__ A3g,
    const f16* __restrict__ LEg, const float* __restrict__ Dv,
    f16* __restrict__ yg) {
  __shared__ f16 As3[64 * 128];   // swizzled (global pre-swizzled)
  __shared__ f16 Bs[64 * 128];    // [col=blk][k], chunk' = chunk ^ (blk&15)
  __shared__ f16 Ys[64 * 72];     // [blk][t] staging, padded
  const int tid = threadIdx.x, wid = tid >> 6, lane = tid & 63;
  const int h = blockIdx.x;
  const float Dh = Dv[h];

#pragma unroll
  for (int q = 0; q < 4; ++q)
    __builtin_amdgcn_global_load_lds((const gvoid*)(A3g + (size_t)h * 8192 + (q * 256 + tid) * 8),
                                     (lvoid*)&As3[(q * 256 + wid * 64) * 8], 16, 0, 0);
  asm volatile("s_waitcnt vmcnt(0)" ::: "memory");

  for (int b = 0; b < 8; ++b) {
    // stage u (f32 -> f16) into k=0..63
#pragma unroll
    for (int i = 0; i < 4; ++i) {
      int e = (i * 256 + tid) * 4;          // 0..4095
      float4 uv = *(const float4*)(u + ((size_t)(b * Hn + h)) * Ln + e);
      int blk = e >> 6, j = e & 63;
      f16x4 hv = {(f16)uv.x, (f16)uv.y, (f16)uv.z, (f16)uv.w};
      *(f16x4*)&Bs[blk * 128 + (((j >> 3) ^ (blk & 15)) * 8) + (j & 7)] = hv;
    }
    // stage E into k=64..127
#pragma unroll
    for (int i = 0; i < 2; ++i) {
      int f = (i * 256 + tid) * 8;          // 0..4095
      int blk = f >> 6, st = f & 63;
      f16x8 ev = *(const f16x8*)(LEg + ((size_t)(h * 8 + b) * 64 + blk) * 64 + st);
      *(f16x8*)&Bs[blk * 128 + (((8 + (st >> 3)) ^ (blk & 15)) * 8)] = ev;
    }
    __syncthreads();

    f32x4 acc[4];
#pragma unroll
    for (int i = 0; i < 4; ++i) acc[i] = (f32x4){0.f, 0.f, 0.f, 0.f};
#pragma unroll
    for (int ks = 0; ks < 4; ++ks) {
      const int kc = ks * 4 + (lane >> 4);    // chunk 0..15
      int col = wid * 16 + (lane & 15);
      f16x8 bf = *(const f16x8*)&Bs[col * 128 + ((kc ^ (col & 15)) * 8)];
#pragma unroll
      for (int mf = 0; mf < 4; ++mf) {
        int row = mf * 16 + (lane & 15);
        f16x8 af = *(const f16x8*)&As3[row * 128 + ((kc ^ (row & 7)) * 8)];
        acc[mf] = __builtin_amdgcn_mfma_f32_16x16x32_f16(af, bf, acc[mf], 0, 0, 0);
      }
    }
    // epilogue: v = y + D*u; GELU; -> Ys[blk][t]
    const int blk = wid * 16 + (lane & 15), t0 = (lane >> 4) * 4;
#pragma unroll
    for (int mf = 0; mf < 4; ++mf) {
      const int tb = mf * 16 + t0;
      f16x4 o;
#pragma unroll
      for (int r = 0; r < 4; ++r) {
        const int t = tb + r;
        float uval = (float)Bs[blk * 128 + (((t >> 3) ^ (blk & 15)) * 8) + (t & 7)];
        float v = acc[mf][r] + Dh * uval;
        o[r] = (f16)(0.5f * v * (1.0f + erff(v * 0.70710678118654752f)));
      }
      *(f16x4*)&Ys[blk * 72 + tb] = o;
    }
    __syncthreads();
#pragma unroll
    for (int i = 0; i < 2; ++i) {
      int f = (i * 256 + tid) * 8;
      int blk2 = f >> 6, t2 = f & 63;
      f16x8 yv = *(const f16x8*)&Ys[blk2 * 72 + t2];
      *(f16x8*)(yg + ((size_t)(b * Hn + h)) * Ln + f) = yv;
    }
    __syncthreads();
  }
}

// ============ K5: transpose y[b][h][l] -> gyT[b][l][h] ============
__global__ __launch_bounds__(256) void k_transpose(
    const f16* __restrict__ yg, f16* __restrict__ gyT) {
  __shared__ float T[64][65];   // [l][h], padded: FIXED (was 64*33 with row-stride 33 overflow)
  const int bid = blockIdx.x, tid = threadIdx.x;
  const int b = bid >> 9, hg = (bid >> 6) & 7, lg = bid & 63;
  const int h0 = hg * 64, l0 = lg * 64;
  const int hi = tid >> 2, lc = (tid & 3) * 16;
  const f16* src = yg + ((size_t)(b * Hn + h0 + hi)) * Ln + l0 + lc;
  f16x8 v0 = *(const f16x8*)src;
  f16x8 v1 = *(const f16x8*)(src + 8);
#pragma unroll
  for (int e = 0; e < 8; ++e) T[lc + e][hi] = (float)v0[e];
#pragma unroll
  for (int e = 0; e < 8; ++e) T[lc + 8 + e][hi] = (float)v1[e];
  __syncthreads();
  const int li = tid >> 2, hc = (tid & 3) * 16;
  f16x8 o0, o1;
#pragma unroll
  for (int e = 0; e < 8; ++e) o0[e] = (f16)T[li][hc + e];
#pragma unroll
  for (int e = 0; e < 8; ++e) o1[e] = (f16)T[li][hc + 8 + e];
  f16* dst = gyT + ((size_t)b * Ln + l0 + li) * Hn + h0 + hc;
  *(f16x8*)dst = o0;
  *(f16x8*)(dst + 8) = o1;
}

// ============ K6: dual GEMM (a,g) + bias + GLU ============
__global__ __launch_bounds__(256, 2) void s4d_gemm(
    const f16* __restrict__ Wh, const f16* __restrict__ gyT,
    const float* __restrict__ bias, float* __restrict__ out) {
  __shared__ f16 As[2][128][64];
  __shared__ f16 Bs[128][64];
  const int tid = threadIdx.x;
  const int wid = tid >> 6, lane = tid & 63;
  const int ntg = blockIdx.x & 255;
  const int mt = blockIdx.x >> 8;
  const int b = ntg >> 5;
  const int l0 = (ntg & 31) * 128;
  const int m0 = mt * 128;
  const int wm = wid >> 1, wn = wid & 1;

  f32x4 acc[2][4][4];
#pragma unroll
  for (int a = 0; a < 2; ++a)
#pragma unroll
    for (int i = 0; i < 4; ++i)
#pragma unroll
      for (int j = 0; j < 4; ++j) acc[a][i][j] = (f32x4){0.f, 0.f, 0.f, 0.f};

  const int srow = lane >> 3;
  const int sk = (lane & 7) * 8;

  for (int kt = 0; kt < 8; ++kt) {
    const int k0 = kt * 64;
#pragma unroll
    for (int q = 0; q < 4; ++q) {
      const int r8 = wid * 32 + q * 8;
      const f16* srcA = Wh + ((size_t)(m0 + r8 + srow) * 512 + k0 + sk);
      __builtin_amdgcn_global_load_lds((const gvoid*)srcA, (lvoid*)&As[0][r8][0], 16, 0, 0);
      const f16* srcG = Wh + ((size_t)(Hn + m0 + r8 + srow) * 512 + k0 + sk);
      __builtin_amdgcn_global_load_lds((const gvoid*)srcG, (lvoid*)&As[1][r8][0], 16, 0, 0);
      const f16* srcB = gyT + (((size_t)b * Ln + l0 + r8 + srow) * Hn + k0 + sk);
      __builtin_amdgcn_global_load_lds((const gvoid*)srcB, (lvoid*)&Bs[r8][0], 16, 0, 0);
    }
    asm volatile("s_waitcnt vmcnt(0)" ::: "memory");
    __syncthreads();
#pragma unroll
    for (int kk = 0; kk < 2; ++kk) {
      const int koff = kk * 32 + (lane >> 4) * 8;
      f16x8 af0[4], af1[4], bfv[4];
#pragma unroll
      for (int mf = 0; mf < 4; ++mf) {
        af0[mf] = *(const f16x8*)&As[0][wm * 64 + mf * 16 + (lane & 15)][koff];
        af1[mf] = *(const f16x8*)&As[1][wm * 64 + mf * 16 + (lane & 15)][koff];
      }
#pragma unroll
      for (int nf = 0; nf < 4; ++nf)
        bfv[nf] = *(const f16x8*)&Bs[wn * 64 + nf * 16 + (lane & 15)][koff];
#pragma unroll
      for (int mf = 0; mf < 4; ++mf)
#pragma unroll
        for (int nf = 0; nf < 4; ++nf) {
          acc[0][mf][nf] = __builtin_amdgcn_mfma_f32_16x16x32_f16(af0[mf], bfv[nf], acc[0][mf][nf], 0, 0, 0);
          acc[1][mf][nf] = __builtin_amdgcn_mfma_f32_16x16x32_f16(af1[mf], bfv[nf], acc[1][mf][nf], 0, 0, 0);
        }
    }
    __syncthreads();
  }

  const int col = lane & 15, r0 = (lane >> 4) * 4;
#pragma unroll
  for (int mf = 0; mf < 4; ++mf) {
    const int hbase = m0 + wm * 64 + mf * 16 + r0;
#pragma unroll
    for (int nf = 0; nf < 4; ++nf) {
      const int l = l0 + wn * 64 + nf * 16 + col;
      f32x4 va = acc[0][mf][nf], vg = acc[1][mf][nf];
#pragma unroll
      for (int r = 0; r < 4; ++r) {
        const int hh = hbase + r;
        float av = va[r] + bias[hh];
        float gv = vg[r] + bias[Hn + hh];
        out[((size_t)b * Hn + hh) * Ln + l] = av / (1.0f + expf(-gv));
      }
    }
  }
}

extern "C" void kernel_launch(void* const* d_in, const int* in_sizes, int n_in,
                              void* d_out, int out_size, void* d_ws, size_t ws_size,
                              hipStream_t stream) {
  (void)in_sizes; (void)n_in; (void)out_size; (void)ws_size;
  const float* u     = (const float*)d_in[0];
  const float* C     = (const float*)d_in[1];
  const float* logdt = (const float*)d_in[2];
  const float* logA  = (const float*)d_in[3];
  const float* Aim   = (const float*)d_in[4];
  const float* Dv    = (const float*)d_in[5];
  const float* W     = (const float*)d_in[6];
  const float* bias  = (const float*)d_in[7];
  float* out = (float*)d_out;

  char* ws = (char*)d_ws;
  f16*    LEg  = (f16*)ws;                                  // 32 MB (L -> Einit -> gyT)
  f16*    Vg   = (f16*)(ws + (size_t)(32 << 20));           // 4 MB
  f16*    A3g  = (f16*)(ws + (size_t)(36 << 20));           // 8 MB
  float*  kg   = (float*)(ws + (size_t)(44 << 20));         // 128 KB
  float2* w64g = (float2*)(ws + (size_t)(44 << 20) + (128 << 10));  // 128 KB
  f16*    Wh   = (f16*)(ws + (size_t)(45 << 20));           // 1 MB
  f16*    gyT  = LEg;                                       // reuse (Einit dead)
  f16*    yg   = (f16*)d_out;                               // 32 MB of d_out, dead before K6 writes

  hipLaunchKernelGGL(k_mats1, dim3(Hn), dim3(64), 0, stream, C, logdt, logA, Aim, Vg, A3g, kg, w64g);
  hipLaunchKernelGGL(k_mats2, dim3(Hn * 4096 / 256), dim3(256), 0, stream, kg, A3g);
  hipLaunchKernelGGL(conv_w, dim3(2048), dim3(256), 0, stream, W, Wh);
  hipLaunchKernelGGL(s4d_phase1, dim3(Hn), dim3(256), 0, stream, u, Vg, LEg);
  hipLaunchKernelGGL(scan64, dim3(Hn * Bn * N2n / 256), dim3(256), 0, stream, LEg, w64g);
  hipLaunchKernelGGL(s4d_phase3, dim3(Hn), dim3(256), 0, stream, u, A3g, LEg, Dv, yg);
  hipLaunchKernelGGL(k_transpose, dim3(Bn * 8 * 64), dim3(256), 0, stream, yg, gyT);
  hipLaunchKernelGGL(s4d_gemm, dim3(4 * 256), dim3(256), 0, stream, Wh, gyT, bias, out);
}

// Round 6
// 129.747 us; speedup vs baseline: 1.9173x; 1.1740x over previous
//
#include <hip/hip_runtime.h>
#include <hip/hip_bf16.h>

constexpr int Bn = 8, Hn = 512, Ln = 4096, N2n = 32;

typedef _Float16 f16;
typedef __attribute__((ext_vector_type(8))) _Float16 f16x8;
typedef __attribute__((ext_vector_type(4))) _Float16 f16x4;
typedef __attribute__((ext_vector_type(2))) _Float16 f16x2;
typedef __attribute__((ext_vector_type(4))) float f32x4;

typedef void __attribute__((address_space(1))) gvoid;
typedef void __attribute__((address_space(3))) lvoid;

// ============ K0: per-h param matrices (V, full A3 incl Toeplitz, w64) ============
// V[h][st][j]  (64x64, swizzled chunks): st=2n -> Re(w^(63-j)), 2n+1 -> Im
// A3[h][t][k]  (64x128, swizzled): k<64 = Toeplitz k[t-j]; k>=64: [64+2n]=Re(C2 w^(t+1)),
//              [64+2n+1]=-Im(C2 w^(t+1)).  Swizzle: chunk' = chunk ^ (row & 7).
__global__ __launch_bounds__(64) void k_mats1(
    const float* __restrict__ C, const float* __restrict__ log_dt,
    const float* __restrict__ logA, const float* __restrict__ Aim,
    f16* __restrict__ Vg, f16* __restrict__ A3g, float2* __restrict__ w64g) {
  __shared__ f16 VT[64 * 64];
  __shared__ f16 QT[64 * 64];
  __shared__ float kp[64][33];
  __shared__ float ks[64];
  const int h = blockIdx.x, tid = threadIdx.x, n = tid & 31;

  if (tid < 32) {
    const int idx = h * N2n + n;
    float dt = expf(log_dt[h]);
    float Ar = -expf(logA[idx]);
    float Ai = Aim[idx];
    float dr = Ar * dt, di = Ai * dt;
    float er = expf(dr);
    float wr = er * cosf(di), wi = er * sinf(di);
    float den = Ar * Ar + Ai * Ai;
    float e1r = wr - 1.0f, e1i = wi;
    float tr = (e1r * Ar + e1i * Ai) / den;
    float ti = (e1i * Ar - e1r * Ai) / den;
    float Cr = C[idx * 2 + 0], Ci = C[idx * 2 + 1];
    float c2r = 2.0f * (Cr * tr - Ci * ti);
    float c2i = 2.0f * (Cr * ti + Ci * tr);

    float wpr = 1.f, wpi = 0.f;   // w^p
    for (int p = 0; p <= 64; ++p) {
      float cwr = c2r * wpr - c2i * wpi;   // C2 * w^p
      float cwi = c2r * wpi + c2i * wpr;
      if (p < 64) {
        const int j = 63 - p, ch = j >> 3, jo = j & 7;
        const int s0 = 2 * n, s1 = 2 * n + 1;
        VT[s0 * 64 + ((ch ^ (s0 & 7)) * 8) + jo] = (f16)wpr;
        VT[s1 * 64 + ((ch ^ (s1 & 7)) * 8) + jo] = (f16)wpi;
        kp[p][n] = cwr;
      }
      if (p >= 1) {
        const int t = p - 1, c0 = 2 * n;
        const int ch = (c0 >> 3) ^ (t & 7);
        QT[t * 64 + ch * 8 + (c0 & 7)]     = (f16)cwr;
        QT[t * 64 + ch * 8 + (c0 & 7) + 1] = (f16)(-cwi);
      }
      if (p == 64) w64g[h * 32 + n] = make_float2(wpr, wpi);
      float nr = wpr * wr - wpi * wi;
      float ni = wpr * wi + wpi * wr;
      wpr = nr; wpi = ni;
    }
  }
  __syncthreads();
  float s = 0.f;
#pragma unroll
  for (int m = 0; m < 32; ++m) s += kp[tid][m];
  ks[tid] = s;
  __syncthreads();
  // Toeplitz rows: t = tid, A3[t][j] = k[t-j] (j<=t), swizzled chunk^(t&7)
  const int t = tid;
#pragma unroll
  for (int c = 0; c < 8; ++c) {
    f16x8 row;
#pragma unroll
    for (int jo = 0; jo < 8; ++jo) {
      int j = c * 8 + jo;
      row[jo] = (j <= t) ? (f16)ks[t - j] : (f16)0.f;
    }
    *(f16x8*)&A3g[(size_t)h * 8192 + t * 128 + ((c ^ (t & 7)) * 8)] = row;
  }
#pragma unroll
  for (int c = 0; c < 8; ++c)
    *(f16x8*)&Vg[(size_t)h * 4096 + tid * 64 + c * 8] = *(f16x8*)&VT[tid * 64 + c * 8];
#pragma unroll
  for (int c = 0; c < 8; ++c)
    *(f16x8*)&A3g[(size_t)h * 8192 + tid * 128 + 64 + c * 8] = *(f16x8*)&QT[tid * 64 + c * 8];
}

// ============ K1: W fp32 -> f16 ============
__global__ void conv_w(const float* __restrict__ W, f16* __restrict__ Wh) {
  int i = blockIdx.x * 256 + threadIdx.x;
  if (i < 2 * Hn * Hn) Wh[i] = (f16)W[i];
}

// ============ K2: L = V·u per h + fused 64-block scan -> E in LEg ============
__global__ __launch_bounds__(256) void s4d_phase1(
    const float* __restrict__ u, const f16* __restrict__ Vg,
    const float2* __restrict__ w64g, f16* __restrict__ LEg) {
  __shared__ f16 As[64 * 64];     // V_h, swizzled (global pre-swizzled)
  __shared__ f16 Bs[512 * 64];    // u staging, then reused as L/E buffer
  const int tid = threadIdx.x, wid = tid >> 6, lane = tid & 63;
  const int h = blockIdx.x;

#pragma unroll
  for (int q = 0; q < 2; ++q)
    __builtin_amdgcn_global_load_lds((const gvoid*)(Vg + (size_t)h * 4096 + (q * 256 + tid) * 8),
                                     (lvoid*)&As[(q * 256 + wid * 64) * 8], 16, 0, 0);
#pragma unroll
  for (int i = 0; i < 32; ++i) {
    int e = (i * 256 + tid) * 4;          // 0..32767
    int b = e >> 12, l = e & 4095;
    float4 uv = *(const float4*)(u + ((size_t)(b * Hn + h)) * Ln + l);
    int col = b * 64 + (l >> 6), j = l & 63;
    f16x4 hv = {(f16)uv.x, (f16)uv.y, (f16)uv.z, (f16)uv.w};
    *(f16x4*)&Bs[col * 64 + ((j >> 3) ^ (col & 7)) * 8 + (j & 7)] = hv;
  }
  asm volatile("s_waitcnt vmcnt(0)" ::: "memory");
  __syncthreads();

  f32x4 acc[4][8];
#pragma unroll
  for (int i = 0; i < 4; ++i)
#pragma unroll
    for (int j = 0; j < 8; ++j) acc[i][j] = (f32x4){0.f, 0.f, 0.f, 0.f};

#pragma unroll
  for (int ks = 0; ks < 2; ++ks) {
    const int kc = ks * 4 + (lane >> 4);        // k-chunk 0..7
    f16x8 a[4], bv[8];
#pragma unroll
    for (int mf = 0; mf < 4; ++mf) {
      int row = mf * 16 + (lane & 15);
      a[mf] = *(const f16x8*)&As[row * 64 + ((kc ^ (row & 7)) * 8)];
    }
#pragma unroll
    for (int nf = 0; nf < 8; ++nf) {
      int col = wid * 128 + nf * 16 + (lane & 15);
      bv[nf] = *(const f16x8*)&Bs[col * 64 + ((kc ^ (col & 7)) * 8)];
    }
#pragma unroll
    for (int mf = 0; mf < 4; ++mf)
#pragma unroll
      for (int nf = 0; nf < 8; ++nf)
        acc[mf][nf] = __builtin_amdgcn_mfma_f32_16x16x32_f16(a[mf], bv[nf], acc[mf][nf], 0, 0, 0);
  }
  __syncthreads();   // all Bs reads complete; Bs now reused as LE

  // write L frags into LE (= Bs), granule-swizzled: granule g(8B) at g^(col&15)
  f16* LE = Bs;
#pragma unroll
  for (int mf = 0; mf < 4; ++mf) {
    int st0 = mf * 16 + (lane >> 4) * 4;
    int g = st0 >> 2;
#pragma unroll
    for (int nf = 0; nf < 8; ++nf) {
      int col = wid * 128 + nf * 16 + (lane & 15);
      f16x4 o = {(f16)acc[mf][nf][0], (f16)acc[mf][nf][1], (f16)acc[mf][nf][2], (f16)acc[mf][nf][3]};
      *(f16x4*)&LE[col * 64 + ((g ^ (col & 15)) << 2)] = o;
    }
  }
  __syncthreads();

  // in-LDS scan over 64 blocks: unit = (b = tid>>5, n = tid&31); L -> E (in place)
  {
    const int b = tid >> 5, n = tid & 31;
    const float2 wT = w64g[h * 32 + n];
    float er = 0.f, ei = 0.f;
    for (int blk = 0; blk < 64; ++blk) {
      const int col = b * 64 + blk;
      const int fi = col * 64 + (((n >> 1) ^ (col & 15)) << 2) + (n & 1) * 2;
      f16x2 Lv = *(const f16x2*)&LE[fi];
      *(f16x2*)&LE[fi] = (f16x2){(f16)er, (f16)ei};
      float nr = fmaf(wT.x, er, fmaf(-wT.y, ei, (float)Lv[0]));
      float ni = fmaf(wT.y, er, fmaf(wT.x, ei, (float)Lv[1]));
      er = nr; ei = ni;
    }
  }
  __syncthreads();

  // copy out, unswizzling: logical 16B chunk e = (col, s8) <- granules 2s8^c, 2s8^c^1
#pragma unroll
  for (int i = 0; i < 16; ++i) {
    int e = i * 256 + tid;                 // 0..4095 16B chunks
    int col = e >> 3, s8 = e & 7, c = col & 15;
    int gb = (2 * s8) ^ c;
    uint4 vv = *(const uint4*)&LE[col * 64 + ((gb & ~1) << 2)];
    uint4 ov = (c & 1) ? make_uint4(vv.z, vv.w, vv.x, vv.y) : vv;
    *(uint4*)&LEg[(size_t)h * 32768 + (size_t)e * 8] = ov;
  }
}

// ============ K4: y = [Tri|Q]·[u;E] + D·u, GELU -> y[b][h][l] f16 ============
__global__ __launch_bounds__(256) void s4d_phase3(
    const float* __restrict__ u, const f16* __restrict__ A3g,
    const f16* __restrict__ LEg, const float* __restrict__ Dv,
    f16* __restrict__ yg) {
  __shared__ f16 As3[64 * 128];   // swizzled (global pre-swizzled)
  __shared__ f16 Bs[64 * 128];    // [col=blk][k], chunk' = chunk ^ (blk&15)
  __shared__ f16 Ys[64 * 72];     // [blk][t] staging, padded
  const int tid = threadIdx.x, wid = tid >> 6, lane = tid & 63;
  const int h = blockIdx.x;
  const float Dh = Dv[h];

#pragma unroll
  for (int q = 0; q < 4; ++q)
    __builtin_amdgcn_global_load_lds((const gvoid*)(A3g + (size_t)h * 8192 + (q * 256 + tid) * 8),
                                     (lvoid*)&As3[(q * 256 + wid * 64) * 8], 16, 0, 0);
  asm volatile("s_waitcnt vmcnt(0)" ::: "memory");

  for (int b = 0; b < 8; ++b) {
    // stage u (f32 -> f16) into k=0..63
#pragma unroll
    for (int i = 0; i < 4; ++i) {
      int e = (i * 256 + tid) * 4;          // 0..4095
      float4 uv = *(const float4*)(u + ((size_t)(b * Hn + h)) * Ln + e);
      int blk = e >> 6, j = e & 63;
      f16x4 hv = {(f16)uv.x, (f16)uv.y, (f16)uv.z, (f16)uv.w};
      *(f16x4*)&Bs[blk * 128 + (((j >> 3) ^ (blk & 15)) * 8) + (j & 7)] = hv;
    }
    // stage E into k=64..127
#pragma unroll
    for (int i = 0; i < 2; ++i) {
      int f = (i * 256 + tid) * 8;          // 0..4095
      int blk = f >> 6, st = f & 63;
      f16x8 ev = *(const f16x8*)(LEg + ((size_t)(h * 8 + b) * 64 + blk) * 64 + st);
      *(f16x8*)&Bs[blk * 128 + (((8 + (st >> 3)) ^ (blk & 15)) * 8)] = ev;
    }
    __syncthreads();

    f32x4 acc[4];
#pragma unroll
    for (int i = 0; i < 4; ++i) acc[i] = (f32x4){0.f, 0.f, 0.f, 0.f};
#pragma unroll
    for (int ks = 0; ks < 4; ++ks) {
      const int kc = ks * 4 + (lane >> 4);    // chunk 0..15
      int col = wid * 16 + (lane & 15);
      f16x8 bf = *(const f16x8*)&Bs[col * 128 + ((kc ^ (col & 15)) * 8)];
#pragma unroll
      for (int mf = 0; mf < 4; ++mf) {
        int row = mf * 16 + (lane & 15);
        f16x8 af = *(const f16x8*)&As3[row * 128 + ((kc ^ (row & 7)) * 8)];
        acc[mf] = __builtin_amdgcn_mfma_f32_16x16x32_f16(af, bf, acc[mf], 0, 0, 0);
      }
    }
    // epilogue: v = y + D*u; GELU; -> Ys[blk][t]
    const int blk = wid * 16 + (lane & 15), t0 = (lane >> 4) * 4;
#pragma unroll
    for (int mf = 0; mf < 4; ++mf) {
      const int tb = mf * 16 + t0;
      f16x4 o;
#pragma unroll
      for (int r = 0; r < 4; ++r) {
        const int t = tb + r;
        float uval = (float)Bs[blk * 128 + (((t >> 3) ^ (blk & 15)) * 8) + (t & 7)];
        float v = acc[mf][r] + Dh * uval;
        o[r] = (f16)(0.5f * v * (1.0f + erff(v * 0.70710678118654752f)));
      }
      *(f16x4*)&Ys[blk * 72 + tb] = o;
    }
    __syncthreads();
#pragma unroll
    for (int i = 0; i < 2; ++i) {
      int f = (i * 256 + tid) * 8;
      int blk2 = f >> 6, t2 = f & 63;
      f16x8 yv = *(const f16x8*)&Ys[blk2 * 72 + t2];
      *(f16x8*)(yg + ((size_t)(b * Hn + h)) * Ln + f) = yv;
    }
    __syncthreads();
  }
}

// ============ K5: transpose y[b][h][l] -> gyT[b][l][h] ============
__global__ __launch_bounds__(256) void k_transpose(
    const f16* __restrict__ yg, f16* __restrict__ gyT) {
  __shared__ float T[64][65];
  const int bid = blockIdx.x, tid = threadIdx.x;
  const int b = bid >> 9, hg = (bid >> 6) & 7, lg = bid & 63;
  const int h0 = hg * 64, l0 = lg * 64;
  const int hi = tid >> 2, lc = (tid & 3) * 16;
  const f16* src = yg + ((size_t)(b * Hn + h0 + hi)) * Ln + l0 + lc;
  f16x8 v0 = *(const f16x8*)src;
  f16x8 v1 = *(const f16x8*)(src + 8);
#pragma unroll
  for (int e = 0; e < 8; ++e) T[lc + e][hi] = (float)v0[e];
#pragma unroll
  for (int e = 0; e < 8; ++e) T[lc + 8 + e][hi] = (float)v1[e];
  __syncthreads();
  const int li = tid >> 2, hc = (tid & 3) * 16;
  f16x8 o0, o1;
#pragma unroll
  for (int e = 0; e < 8; ++e) o0[e] = (f16)T[li][hc + e];
#pragma unroll
  for (int e = 0; e < 8; ++e) o1[e] = (f16)T[li][hc + 8 + e];
  f16* dst = gyT + ((size_t)b * Ln + l0 + li) * Hn + h0 + hc;
  *(f16x8*)dst = o0;
  *(f16x8*)(dst + 8) = o1;
}

// ============ K6: dual GEMM (a,g) + bias + GLU — swizzled LDS ============
// Staging: inverse-swizzled global source (chunk ck^srow) + linear LDS dest
//   => LDS[row][p] = G[row][p ^ (row&7)]; reads use chunk kc ^ (row&7).
__global__ __launch_bounds__(256, 2) void s4d_gemm(
    const f16* __restrict__ Wh, const f16* __restrict__ gyT,
    const float* __restrict__ bias, float* __restrict__ out) {
  __shared__ f16 As[2][128][64];
  __shared__ f16 Bs[128][64];
  const int tid = threadIdx.x;
  const int wid = tid >> 6, lane = tid & 63;
  const int ntg = blockIdx.x & 255;
  const int mt = blockIdx.x >> 8;
  const int b = ntg >> 5;
  const int l0 = (ntg & 31) * 128;
  const int m0 = mt * 128;
  const int wm = wid >> 1, wn = wid & 1;

  f32x4 acc[2][4][4];
#pragma unroll
  for (int a = 0; a < 2; ++a)
#pragma unroll
    for (int i = 0; i < 4; ++i)
#pragma unroll
      for (int j = 0; j < 4; ++j) acc[a][i][j] = (f32x4){0.f, 0.f, 0.f, 0.f};

  const int srow = lane >> 3;              // row within 8-row group
  const int sks = ((lane & 7) ^ srow) * 8; // inverse-swizzled source k-offset

  for (int kt = 0; kt < 8; ++kt) {
    const int k0 = kt * 64;
#pragma unroll
    for (int q = 0; q < 4; ++q) {
      const int r8 = wid * 32 + q * 8;
      const f16* srcA = Wh + ((size_t)(m0 + r8 + srow) * 512 + k0 + sks);
      __builtin_amdgcn_global_load_lds((const gvoid*)srcA, (lvoid*)&As[0][r8][0], 16, 0, 0);
      const f16* srcG = Wh + ((size_t)(Hn + m0 + r8 + srow) * 512 + k0 + sks);
      __builtin_amdgcn_global_load_lds((const gvoid*)srcG, (lvoid*)&As[1][r8][0], 16, 0, 0);
      const f16* srcB = gyT + (((size_t)b * Ln + l0 + r8 + srow) * Hn + k0 + sks);
      __builtin_amdgcn_global_load_lds((const gvoid*)srcB, (lvoid*)&Bs[r8][0], 16, 0, 0);
    }
    asm volatile("s_waitcnt vmcnt(0)" ::: "memory");
    __syncthreads();
#pragma unroll
    for (int kk = 0; kk < 2; ++kk) {
      const int kc = kk * 4 + (lane >> 4);   // logical k-chunk
      f16x8 af0[4], af1[4], bfv[4];
#pragma unroll
      for (int mf = 0; mf < 4; ++mf) {
        const int row = wm * 64 + mf * 16 + (lane & 15);
        af0[mf] = *(const f16x8*)&As[0][row][(kc ^ (row & 7)) * 8];
        af1[mf] = *(const f16x8*)&As[1][row][(kc ^ (row & 7)) * 8];
      }
#pragma unroll
      for (int nf = 0; nf < 4; ++nf) {
        const int col = wn * 64 + nf * 16 + (lane & 15);
        bfv[nf] = *(const f16x8*)&Bs[col][(kc ^ (col & 7)) * 8];
      }
#pragma unroll
      for (int mf = 0; mf < 4; ++mf)
#pragma unroll
        for (int nf = 0; nf < 4; ++nf) {
          acc[0][mf][nf] = __builtin_amdgcn_mfma_f32_16x16x32_f16(af0[mf], bfv[nf], acc[0][mf][nf], 0, 0, 0);
          acc[1][mf][nf] = __builtin_amdgcn_mfma_f32_16x16x32_f16(af1[mf], bfv[nf], acc[1][mf][nf], 0, 0, 0);
        }
    }
    __syncthreads();
  }

  const int col = lane & 15, r0 = (lane >> 4) * 4;
#pragma unroll
  for (int mf = 0; mf < 4; ++mf) {
    const int hbase = m0 + wm * 64 + mf * 16 + r0;
#pragma unroll
    for (int nf = 0; nf < 4; ++nf) {
      const int l = l0 + wn * 64 + nf * 16 + col;
      f32x4 va = acc[0][mf][nf], vg = acc[1][mf][nf];
#pragma unroll
      for (int r = 0; r < 4; ++r) {
        const int hh = hbase + r;
        float av = va[r] + bias[hh];
        float gv = vg[r] + bias[Hn + hh];
        out[((size_t)b * Hn + hh) * Ln + l] = av / (1.0f + expf(-gv));
      }
    }
  }
}

extern "C" void kernel_launch(void* const* d_in, const int* in_sizes, int n_in,
                              void* d_out, int out_size, void* d_ws, size_t ws_size,
                              hipStream_t stream) {
  (void)in_sizes; (void)n_in; (void)out_size; (void)ws_size;
  const float* u     = (const float*)d_in[0];
  const float* C     = (const float*)d_in[1];
  const float* logdt = (const float*)d_in[2];
  const float* logA  = (const float*)d_in[3];
  const float* Aim   = (const float*)d_in[4];
  const float* Dv    = (const float*)d_in[5];
  const float* W     = (const float*)d_in[6];
  const float* bias  = (const float*)d_in[7];
  float* out = (float*)d_out;

  char* ws = (char*)d_ws;
  f16*    LEg  = (f16*)ws;                                  // 32 MB (E, then gyT)
  f16*    Vg   = (f16*)(ws + (size_t)(32 << 20));           // 4 MB
  f16*    A3g  = (f16*)(ws + (size_t)(36 << 20));           // 8 MB
  float2* w64g = (float2*)(ws + (size_t)(44 << 20));        // 128 KB
  f16*    Wh   = (f16*)(ws + (size_t)(45 << 20));           // 1 MB
  f16*    gyT  = LEg;                                       // reuse (E consumed by phase3)
  f16*    yg   = (f16*)d_out;                               // dead before K6 writes

  hipLaunchKernelGGL(k_mats1, dim3(Hn), dim3(64), 0, stream, C, logdt, logA, Aim, Vg, A3g, w64g);
  hipLaunchKernelGGL(conv_w, dim3(2048), dim3(256), 0, stream, W, Wh);
  hipLaunchKernelGGL(s4d_phase1, dim3(Hn), dim3(256), 0, stream, u, Vg, w64g, LEg);
  hipLaunchKernelGGL(s4d_phase3, dim3(Hn), dim3(256), 0, stream, u, A3g, LEg, Dv, yg);
  hipLaunchKernelGGL(k_transpose, dim3(Bn * 8 * 64), dim3(256), 0, stream, yg, gyT);
  hipLaunchKernelGGL(s4d_gemm, dim3(4 * 256), dim3(256), 0, stream, Wh, gyT, bias, out);
}

// Round 7
// 120.406 us; speedup vs baseline: 2.0660x; 1.0776x over previous
//
#include <hip/hip_runtime.h>
#include <hip/hip_bf16.h>

constexpr int Bn = 8, Hn = 512, Ln = 4096, N2n = 32;

typedef _Float16 f16;
typedef __attribute__((ext_vector_type(8))) _Float16 f16x8;
typedef __attribute__((ext_vector_type(4))) _Float16 f16x4;
typedef __attribute__((ext_vector_type(2))) _Float16 f16x2;
typedef __attribute__((ext_vector_type(4))) float f32x4;

typedef void __attribute__((address_space(1))) gvoid;
typedef void __attribute__((address_space(3))) lvoid;

// ============ K0: per-h param matrices (V, full A3 incl Toeplitz, w64) ============
// V[h][st][j]  (64x64, swizzled chunks): st=2n -> Re(w^(63-j)), 2n+1 -> Im
// A3[h][t][k]  (64x128, swizzled): k<64 = Toeplitz k[t-j]; k>=64: [64+2n]=Re(C2 w^(t+1)),
//              [64+2n+1]=-Im(C2 w^(t+1)).  Swizzle: chunk' = chunk ^ (row & 7).
__global__ __launch_bounds__(64) void k_mats1(
    const float* __restrict__ C, const float* __restrict__ log_dt,
    const float* __restrict__ logA, const float* __restrict__ Aim,
    f16* __restrict__ Vg, f16* __restrict__ A3g, float2* __restrict__ w64g) {
  __shared__ f16 VT[64 * 64];
  __shared__ f16 QT[64 * 64];
  __shared__ float kp[64][33];
  __shared__ float ks[64];
  const int h = blockIdx.x, tid = threadIdx.x, n = tid & 31;

  if (tid < 32) {
    const int idx = h * N2n + n;
    float dt = expf(log_dt[h]);
    float Ar = -expf(logA[idx]);
    float Ai = Aim[idx];
    float dr = Ar * dt, di = Ai * dt;
    float er = expf(dr);
    float wr = er * cosf(di), wi = er * sinf(di);
    float den = Ar * Ar + Ai * Ai;
    float e1r = wr - 1.0f, e1i = wi;
    float tr = (e1r * Ar + e1i * Ai) / den;
    float ti = (e1i * Ar - e1r * Ai) / den;
    float Cr = C[idx * 2 + 0], Ci = C[idx * 2 + 1];
    float c2r = 2.0f * (Cr * tr - Ci * ti);
    float c2i = 2.0f * (Cr * ti + Ci * tr);

    float wpr = 1.f, wpi = 0.f;   // w^p
    for (int p = 0; p <= 64; ++p) {
      float cwr = c2r * wpr - c2i * wpi;   // C2 * w^p
      float cwi = c2r * wpi + c2i * wpr;
      if (p < 64) {
        const int j = 63 - p, ch = j >> 3, jo = j & 7;
        const int s0 = 2 * n, s1 = 2 * n + 1;
        VT[s0 * 64 + ((ch ^ (s0 & 7)) * 8) + jo] = (f16)wpr;
        VT[s1 * 64 + ((ch ^ (s1 & 7)) * 8) + jo] = (f16)wpi;
        kp[p][n] = cwr;
      }
      if (p >= 1) {
        const int t = p - 1, c0 = 2 * n;
        const int ch = (c0 >> 3) ^ (t & 7);
        QT[t * 64 + ch * 8 + (c0 & 7)]     = (f16)cwr;
        QT[t * 64 + ch * 8 + (c0 & 7) + 1] = (f16)(-cwi);
      }
      if (p == 64) w64g[h * 32 + n] = make_float2(wpr, wpi);
      float nr = wpr * wr - wpi * wi;
      float ni = wpr * wi + wpi * wr;
      wpr = nr; wpi = ni;
    }
  }
  __syncthreads();
  float s = 0.f;
#pragma unroll
  for (int m = 0; m < 32; ++m) s += kp[tid][m];
  ks[tid] = s;
  __syncthreads();
  // Toeplitz rows: t = tid, A3[t][j] = k[t-j] (j<=t), swizzled chunk^(t&7)
  const int t = tid;
#pragma unroll
  for (int c = 0; c < 8; ++c) {
    f16x8 row;
#pragma unroll
    for (int jo = 0; jo < 8; ++jo) {
      int j = c * 8 + jo;
      row[jo] = (j <= t) ? (f16)ks[t - j] : (f16)0.f;
    }
    *(f16x8*)&A3g[(size_t)h * 8192 + t * 128 + ((c ^ (t & 7)) * 8)] = row;
  }
#pragma unroll
  for (int c = 0; c < 8; ++c)
    *(f16x8*)&Vg[(size_t)h * 4096 + tid * 64 + c * 8] = *(f16x8*)&VT[tid * 64 + c * 8];
#pragma unroll
  for (int c = 0; c < 8; ++c)
    *(f16x8*)&A3g[(size_t)h * 8192 + tid * 128 + 64 + c * 8] = *(f16x8*)&QT[tid * 64 + c * 8];
}

// ============ K1: W fp32 -> f16 ============
__global__ void conv_w(const float* __restrict__ W, f16* __restrict__ Wh) {
  int i = blockIdx.x * 256 + threadIdx.x;
  if (i < 2 * Hn * Hn) Wh[i] = (f16)W[i];
}

// ============ K2: fused middle: L = V·u -> in-LDS scan -> y = [Tri|Q]·[u;E] ============
// One block per h. LDS: U 64KB [col][j] chunk^(col&7); LE 64KB [col][st] chunk8^(col&7);
// MATS 16KB (V first 8KB, then A3 overwrites).
__global__ __launch_bounds__(256, 1) void s4d_mid(
    const float* __restrict__ u, const f16* __restrict__ Vg,
    const f16* __restrict__ A3g, const float2* __restrict__ w64g,
    const float* __restrict__ Dv, f16* __restrict__ yg) {
  __shared__ f16 MATS[8192];
  __shared__ f16 U[32768];
  __shared__ f16 LE[32768];
  const int tid = threadIdx.x, wid = tid >> 6, lane = tid & 63;
  const int h = blockIdx.x;
  const float Dh = Dv[h];

  // V -> MATS[0..4096)
#pragma unroll
  for (int q = 0; q < 2; ++q)
    __builtin_amdgcn_global_load_lds((const gvoid*)(Vg + (size_t)h * 4096 + (q * 256 + tid) * 8),
                                     (lvoid*)&MATS[(q * 256 + wid * 64) * 8], 16, 0, 0);
  // u staging (f32 -> f16), all 8 batches
#pragma unroll
  for (int i = 0; i < 32; ++i) {
    int e = (i * 256 + tid) * 4;          // 0..32767
    int b = e >> 12, l = e & 4095;
    float4 uv = *(const float4*)(u + ((size_t)(b * Hn + h)) * Ln + l);
    int col = b * 64 + (l >> 6), j = l & 63;
    f16x4 hv = {(f16)uv.x, (f16)uv.y, (f16)uv.z, (f16)uv.w};
    *(f16x4*)&U[col * 64 + ((j >> 3) ^ (col & 7)) * 8 + (j & 7)] = hv;
  }
  asm volatile("s_waitcnt vmcnt(0)" ::: "memory");
  __syncthreads();

  // ---- MFMA1: L = V · u ----
  f32x4 acc[4][8];
#pragma unroll
  for (int i = 0; i < 4; ++i)
#pragma unroll
    for (int j = 0; j < 8; ++j) acc[i][j] = (f32x4){0.f, 0.f, 0.f, 0.f};
#pragma unroll
  for (int ks = 0; ks < 2; ++ks) {
    const int kc = ks * 4 + (lane >> 4);
    f16x8 a[4], bv[8];
#pragma unroll
    for (int mf = 0; mf < 4; ++mf) {
      int row = mf * 16 + (lane & 15);
      a[mf] = *(const f16x8*)&MATS[row * 64 + ((kc ^ (row & 7)) * 8)];
    }
#pragma unroll
    for (int nf = 0; nf < 8; ++nf) {
      int col = wid * 128 + nf * 16 + (lane & 15);
      bv[nf] = *(const f16x8*)&U[col * 64 + ((kc ^ (col & 7)) * 8)];
    }
#pragma unroll
    for (int mf = 0; mf < 4; ++mf)
#pragma unroll
      for (int nf = 0; nf < 8; ++nf)
        acc[mf][nf] = __builtin_amdgcn_mfma_f32_16x16x32_f16(a[mf], bv[nf], acc[mf][nf], 0, 0, 0);
  }
  __syncthreads();   // V reads drained; safe to overwrite MATS

  // issue A3 loads (hide under L-write + scan)
#pragma unroll
  for (int q = 0; q < 4; ++q)
    __builtin_amdgcn_global_load_lds((const gvoid*)(A3g + (size_t)h * 8192 + (q * 256 + tid) * 8),
                                     (lvoid*)&MATS[(q * 256 + wid * 64) * 8], 16, 0, 0);

  // write L frags to LE: [col][st] with 8-f16 chunk swizzle chunk^(col&7)
#pragma unroll
  for (int mf = 0; mf < 4; ++mf) {
    int st0 = mf * 16 + (lane >> 4) * 4;
#pragma unroll
    for (int nf = 0; nf < 8; ++nf) {
      int col = wid * 128 + nf * 16 + (lane & 15);
      f16x4 o = {(f16)acc[mf][nf][0], (f16)acc[mf][nf][1], (f16)acc[mf][nf][2], (f16)acc[mf][nf][3]};
      *(f16x4*)&LE[col * 64 + (((st0 >> 3) ^ (col & 7)) << 3) + (st0 & 7)] = o;
    }
  }
  __syncthreads();

  // ---- in-LDS scan over 64 blocks; unit = (b = tid>>5, n = tid&31) ----
  {
    const int b = tid >> 5, n = tid & 31;
    const float2 wT = w64g[h * 32 + n];
    float er = 0.f, ei = 0.f;
    const int inner = (((n >> 2)) << 3) + ((n & 3) << 1);  // pre-swizzle base (chunk n>>2)
#pragma unroll
    for (int g = 0; g < 8; ++g) {
      f16x2 Lb[8];
#pragma unroll
      for (int k = 0; k < 8; ++k) {
        int blk = g * 8 + k;
        int col = b * 64 + blk;
        int fi = col * 64 + ((((n >> 2) ^ (blk & 7))) << 3) + ((n & 3) << 1);
        Lb[k] = *(const f16x2*)&LE[fi];
      }
#pragma unroll
      for (int k = 0; k < 8; ++k) {
        int blk = g * 8 + k;
        int col = b * 64 + blk;
        int fi = col * 64 + ((((n >> 2) ^ (blk & 7))) << 3) + ((n & 3) << 1);
        *(f16x2*)&LE[fi] = (f16x2){(f16)er, (f16)ei};
        float nr = fmaf(wT.x, er, fmaf(-wT.y, ei, (float)Lb[k][0]));
        float ni = fmaf(wT.y, er, fmaf(wT.x, ei, (float)Lb[k][1]));
        er = nr; ei = ni;
      }
    }
    (void)inner;
  }
  asm volatile("s_waitcnt vmcnt(0)" ::: "memory");   // own A3 loads done
  __syncthreads();                                    // everyone's A3 + E visible

  // ---- per-b y-GEMM: A = A3 (MATS), B = [U | LE] read in place ----
  const int blk = wid * 16 + (lane & 15);
  for (int b = 0; b < 8; ++b) {
    const int col = b * 64 + blk;
    f32x4 acc4[4];
#pragma unroll
    for (int i = 0; i < 4; ++i) acc4[i] = (f32x4){0.f, 0.f, 0.f, 0.f};
#pragma unroll
    for (int ks = 0; ks < 4; ++ks) {
      const int kc = ks * 4 + (lane >> 4);   // 0..15, uniform half per ks
      f16x8 bf;
      if (ks < 2) bf = *(const f16x8*)&U[col * 64 + ((kc ^ (col & 7)) << 3)];
      else        bf = *(const f16x8*)&LE[col * 64 + (((kc - 8) ^ (col & 7)) << 3)];
#pragma unroll
      for (int mf = 0; mf < 4; ++mf) {
        int row = mf * 16 + (lane & 15);
        f16x8 af = *(const f16x8*)&MATS[row * 128 + ((kc ^ (row & 7)) << 3)];
        acc4[mf] = __builtin_amdgcn_mfma_f32_16x16x32_f16(af, bf, acc4[mf], 0, 0, 0);
      }
    }
    // epilogue: v = y + D*u; exact GELU; direct f16x4 stores
    const int t0 = (lane >> 4) * 4;
#pragma unroll
    for (int mf = 0; mf < 4; ++mf) {
      const int tb = mf * 16 + t0;
      f16x4 uq = *(const f16x4*)&U[col * 64 + (((tb >> 3) ^ (col & 7)) << 3) + (tb & 7)];
      f16x4 o;
#pragma unroll
      for (int r = 0; r < 4; ++r) {
        float v = acc4[mf][r] + Dh * (float)uq[r];
        o[r] = (f16)(0.5f * v * (1.0f + erff(v * 0.70710678118654752f)));
      }
      *(f16x4*)&yg[((size_t)(b * Hn + h)) * Ln + blk * 64 + tb] = o;
    }
  }
}

// ============ K5: transpose y[b][h][l] -> gyT[b][l][h] ============
__global__ __launch_bounds__(256) void k_transpose(
    const f16* __restrict__ yg, f16* __restrict__ gyT) {
  __shared__ float T[64][65];
  const int bid = blockIdx.x, tid = threadIdx.x;
  const int b = bid >> 9, hg = (bid >> 6) & 7, lg = bid & 63;
  const int h0 = hg * 64, l0 = lg * 64;
  const int hi = tid >> 2, lc = (tid & 3) * 16;
  const f16* src = yg + ((size_t)(b * Hn + h0 + hi)) * Ln + l0 + lc;
  f16x8 v0 = *(const f16x8*)src;
  f16x8 v1 = *(const f16x8*)(src + 8);
#pragma unroll
  for (int e = 0; e < 8; ++e) T[lc + e][hi] = (float)v0[e];
#pragma unroll
  for (int e = 0; e < 8; ++e) T[lc + 8 + e][hi] = (float)v1[e];
  __syncthreads();
  const int li = tid >> 2, hc = (tid & 3) * 16;
  f16x8 o0, o1;
#pragma unroll
  for (int e = 0; e < 8; ++e) o0[e] = (f16)T[li][hc + e];
#pragma unroll
  for (int e = 0; e < 8; ++e) o1[e] = (f16)T[li][hc + 8 + e];
  f16* dst = gyT + ((size_t)b * Ln + l0 + li) * Hn + h0 + hc;
  *(f16x8*)dst = o0;
  *(f16x8*)(dst + 8) = o1;
}

// ============ K6: dual GEMM (a,g) + bias + GLU — swizzled LDS ============
__global__ __launch_bounds__(256, 2) void s4d_gemm(
    const f16* __restrict__ Wh, const f16* __restrict__ gyT,
    const float* __restrict__ bias, float* __restrict__ out) {
  __shared__ f16 As[2][128][64];
  __shared__ f16 Bs[128][64];
  const int tid = threadIdx.x;
  const int wid = tid >> 6, lane = tid & 63;
  const int ntg = blockIdx.x & 255;
  const int mt = blockIdx.x >> 8;
  const int b = ntg >> 5;
  const int l0 = (ntg & 31) * 128;
  const int m0 = mt * 128;
  const int wm = wid >> 1, wn = wid & 1;

  f32x4 acc[2][4][4];
#pragma unroll
  for (int a = 0; a < 2; ++a)
#pragma unroll
    for (int i = 0; i < 4; ++i)
#pragma unroll
      for (int j = 0; j < 4; ++j) acc[a][i][j] = (f32x4){0.f, 0.f, 0.f, 0.f};

  const int srow = lane >> 3;              // row within 8-row group
  const int sks = ((lane & 7) ^ srow) * 8; // inverse-swizzled source k-offset

  for (int kt = 0; kt < 8; ++kt) {
    const int k0 = kt * 64;
#pragma unroll
    for (int q = 0; q < 4; ++q) {
      const int r8 = wid * 32 + q * 8;
      const f16* srcA = Wh + ((size_t)(m0 + r8 + srow) * 512 + k0 + sks);
      __builtin_amdgcn_global_load_lds((const gvoid*)srcA, (lvoid*)&As[0][r8][0], 16, 0, 0);
      const f16* srcG = Wh + ((size_t)(Hn + m0 + r8 + srow) * 512 + k0 + sks);
      __builtin_amdgcn_global_load_lds((const gvoid*)srcG, (lvoid*)&As[1][r8][0], 16, 0, 0);
      const f16* srcB = gyT + (((size_t)b * Ln + l0 + r8 + srow) * Hn + k0 + sks);
      __builtin_amdgcn_global_load_lds((const gvoid*)srcB, (lvoid*)&Bs[r8][0], 16, 0, 0);
    }
    asm volatile("s_waitcnt vmcnt(0)" ::: "memory");
    __syncthreads();
#pragma unroll
    for (int kk = 0; kk < 2; ++kk) {
      const int kc = kk * 4 + (lane >> 4);   // logical k-chunk
      f16x8 af0[4], af1[4], bfv[4];
#pragma unroll
      for (int mf = 0; mf < 4; ++mf) {
        const int row = wm * 64 + mf * 16 + (lane & 15);
        af0[mf] = *(const f16x8*)&As[0][row][(kc ^ (row & 7)) * 8];
        af1[mf] = *(const f16x8*)&As[1][row][(kc ^ (row & 7)) * 8];
      }
#pragma unroll
      for (int nf = 0; nf < 4; ++nf) {
        const int col = wn * 64 + nf * 16 + (lane & 15);
        bfv[nf] = *(const f16x8*)&Bs[col][(kc ^ (col & 7)) * 8];
      }
#pragma unroll
      for (int mf = 0; mf < 4; ++mf)
#pragma unroll
        for (int nf = 0; nf < 4; ++nf) {
          acc[0][mf][nf] = __builtin_amdgcn_mfma_f32_16x16x32_f16(af0[mf], bfv[nf], acc[0][mf][nf], 0, 0, 0);
          acc[1][mf][nf] = __builtin_amdgcn_mfma_f32_16x16x32_f16(af1[mf], bfv[nf], acc[1][mf][nf], 0, 0, 0);
        }
    }
    __syncthreads();
  }

  const int col = lane & 15, r0 = (lane >> 4) * 4;
#pragma unroll
  for (int mf = 0; mf < 4; ++mf) {
    const int hbase = m0 + wm * 64 + mf * 16 + r0;
#pragma unroll
    for (int nf = 0; nf < 4; ++nf) {
      const int l = l0 + wn * 64 + nf * 16 + col;
      f32x4 va = acc[0][mf][nf], vg = acc[1][mf][nf];
#pragma unroll
      for (int r = 0; r < 4; ++r) {
        const int hh = hbase + r;
        float av = va[r] + bias[hh];
        float gv = vg[r] + bias[Hn + hh];
        float sg = __builtin_amdgcn_rcpf(1.0f + __expf(-gv));
        out[((size_t)b * Hn + hh) * Ln + l] = av * sg;
      }
    }
  }
}

extern "C" void kernel_launch(void* const* d_in, const int* in_sizes, int n_in,
                              void* d_out, int out_size, void* d_ws, size_t ws_size,
                              hipStream_t stream) {
  (void)in_sizes; (void)n_in; (void)out_size; (void)ws_size;
  const float* u     = (const float*)d_in[0];
  const float* C     = (const float*)d_in[1];
  const float* logdt = (const float*)d_in[2];
  const float* logA  = (const float*)d_in[3];
  const float* Aim   = (const float*)d_in[4];
  const float* Dv    = (const float*)d_in[5];
  const float* W     = (const float*)d_in[6];
  const float* bias  = (const float*)d_in[7];
  float* out = (float*)d_out;

  char* ws = (char*)d_ws;
  f16*    gyT  = (f16*)ws;                                  // 32 MB
  f16*    Vg   = (f16*)(ws + (size_t)(32 << 20));           // 4 MB
  f16*    A3g  = (f16*)(ws + (size_t)(36 << 20));           // 8 MB
  float2* w64g = (float2*)(ws + (size_t)(44 << 20));        // 128 KB
  f16*    Wh   = (f16*)(ws + (size_t)(45 << 20));           // 1 MB
  f16*    yg   = (f16*)d_out;                               // dead before K6 writes

  hipLaunchKernelGGL(k_mats1, dim3(Hn), dim3(64), 0, stream, C, logdt, logA, Aim, Vg, A3g, w64g);
  hipLaunchKernelGGL(conv_w, dim3(2048), dim3(256), 0, stream, W, Wh);
  hipLaunchKernelGGL(s4d_mid, dim3(Hn), dim3(256), 0, stream, u, Vg, A3g, w64g, Dv, yg);
  hipLaunchKernelGGL(k_transpose, dim3(Bn * 8 * 64), dim3(256), 0, stream, yg, gyT);
  hipLaunchKernelGGL(s4d_gemm, dim3(4 * 256), dim3(256), 0, stream, Wh, gyT, bias, out);
}

// Round 8
// 112.454 us; speedup vs baseline: 2.2121x; 1.0707x over previous
//
#include <hip/hip_runtime.h>
#include <hip/hip_bf16.h>

constexpr int Bn = 8, Hn = 512, Ln = 4096, N2n = 32;

typedef _Float16 f16;
typedef __attribute__((ext_vector_type(8))) _Float16 f16x8;
typedef __attribute__((ext_vector_type(4))) _Float16 f16x4;
typedef __attribute__((ext_vector_type(2))) _Float16 f16x2;
typedef __attribute__((ext_vector_type(4))) float f32x4;

typedef void __attribute__((address_space(1))) gvoid;
typedef void __attribute__((address_space(3))) lvoid;

// ============ K0: per-h param matrices (V, full A3 incl Toeplitz, w64) ============
// V[h][st][j]  (64x64, swizzled chunks): st=2n -> Re(w^(63-j)), 2n+1 -> Im
// A3[h][t][k]  (64x128, swizzled): k<64 = Toeplitz k[t-j]; k>=64: [64+2n]=Re(C2 w^(t+1)),
//              [64+2n+1]=-Im(C2 w^(t+1)).  Swizzle: chunk' = chunk ^ (row & 7).
__global__ __launch_bounds__(64) void k_mats1(
    const float* __restrict__ C, const float* __restrict__ log_dt,
    const float* __restrict__ logA, const float* __restrict__ Aim,
    f16* __restrict__ Vg, f16* __restrict__ A3g, float2* __restrict__ w64g) {
  __shared__ f16 VT[64 * 64];
  __shared__ f16 QT[64 * 64];
  __shared__ float kp[64][33];
  __shared__ float ks[64];
  const int h = blockIdx.x, tid = threadIdx.x, n = tid & 31;

  if (tid < 32) {
    const int idx = h * N2n + n;
    float dt = expf(log_dt[h]);
    float Ar = -expf(logA[idx]);
    float Ai = Aim[idx];
    float dr = Ar * dt, di = Ai * dt;
    float er = expf(dr);
    float wr = er * cosf(di), wi = er * sinf(di);
    float den = Ar * Ar + Ai * Ai;
    float e1r = wr - 1.0f, e1i = wi;
    float tr = (e1r * Ar + e1i * Ai) / den;
    float ti = (e1i * Ar - e1r * Ai) / den;
    float Cr = C[idx * 2 + 0], Ci = C[idx * 2 + 1];
    float c2r = 2.0f * (Cr * tr - Ci * ti);
    float c2i = 2.0f * (Cr * ti + Ci * tr);

    float wpr = 1.f, wpi = 0.f;   // w^p
    for (int p = 0; p <= 64; ++p) {
      float cwr = c2r * wpr - c2i * wpi;   // C2 * w^p
      float cwi = c2r * wpi + c2i * wpr;
      if (p < 64) {
        const int j = 63 - p, ch = j >> 3, jo = j & 7;
        const int s0 = 2 * n, s1 = 2 * n + 1;
        VT[s0 * 64 + ((ch ^ (s0 & 7)) * 8) + jo] = (f16)wpr;
        VT[s1 * 64 + ((ch ^ (s1 & 7)) * 8) + jo] = (f16)wpi;
        kp[p][n] = cwr;
      }
      if (p >= 1) {
        const int t = p - 1, c0 = 2 * n;
        const int ch = (c0 >> 3) ^ (t & 7);
        QT[t * 64 + ch * 8 + (c0 & 7)]     = (f16)cwr;
        QT[t * 64 + ch * 8 + (c0 & 7) + 1] = (f16)(-cwi);
      }
      if (p == 64) w64g[h * 32 + n] = make_float2(wpr, wpi);
      float nr = wpr * wr - wpi * wi;
      float ni = wpr * wi + wpi * wr;
      wpr = nr; wpi = ni;
    }
  }
  __syncthreads();
  float s = 0.f;
#pragma unroll
  for (int m = 0; m < 32; ++m) s += kp[tid][m];
  ks[tid] = s;
  __syncthreads();
  // Toeplitz rows: t = tid, A3[t][j] = k[t-j] (j<=t), swizzled chunk^(t&7)
  const int t = tid;
#pragma unroll
  for (int c = 0; c < 8; ++c) {
    f16x8 row;
#pragma unroll
    for (int jo = 0; jo < 8; ++jo) {
      int j = c * 8 + jo;
      row[jo] = (j <= t) ? (f16)ks[t - j] : (f16)0.f;
    }
    *(f16x8*)&A3g[(size_t)h * 8192 + t * 128 + ((c ^ (t & 7)) * 8)] = row;
  }
#pragma unroll
  for (int c = 0; c < 8; ++c)
    *(f16x8*)&Vg[(size_t)h * 4096 + tid * 64 + c * 8] = *(f16x8*)&VT[tid * 64 + c * 8];
#pragma unroll
  for (int c = 0; c < 8; ++c)
    *(f16x8*)&A3g[(size_t)h * 8192 + tid * 128 + 64 + c * 8] = *(f16x8*)&QT[tid * 64 + c * 8];
}

// ============ K1: W fp32 -> f16 ============
__global__ void conv_w(const float* __restrict__ W, f16* __restrict__ Wh) {
  int i = blockIdx.x * 256 + threadIdx.x;
  if (i < 2 * Hn * Hn) Wh[i] = (f16)W[i];
}

// ============ K2: fused middle, one block per (h,b): 32 KB LDS ============
// L = V·u -> in-LDS scan -> y = [Tri|Q]·[u;E]
__global__ __launch_bounds__(256, 4) void s4d_mid(
    const float* __restrict__ u, const f16* __restrict__ Vg,
    const f16* __restrict__ A3g, const float2* __restrict__ w64g,
    const float* __restrict__ Dv, f16* __restrict__ yg) {
  __shared__ f16 MATS[8192];   // 16 KB: V in [0:4096), then A3 overwrites
  __shared__ f16 U[4096];      // 8 KB: [col=blk][j] chunk^(col&7)
  __shared__ f16 LE[4096];     // 8 KB: [col=blk][st] chunk^(col&7)
  const int tid = threadIdx.x, wid = tid >> 6, lane = tid & 63;
  const int h = blockIdx.x >> 3, b = blockIdx.x & 7;
  const float Dh = Dv[h];

  // V -> MATS[0..4096)
#pragma unroll
  for (int q = 0; q < 2; ++q)
    __builtin_amdgcn_global_load_lds((const gvoid*)(Vg + (size_t)h * 4096 + (q * 256 + tid) * 8),
                                     (lvoid*)&MATS[(q * 256 + wid * 64) * 8], 16, 0, 0);
  // u staging (f32 -> f16), this batch only
#pragma unroll
  for (int i = 0; i < 4; ++i) {
    int e = (i * 256 + tid) * 4;          // 0..4095
    float4 uv = *(const float4*)(u + ((size_t)(b * Hn + h)) * Ln + e);
    int col = e >> 6, j = e & 63;
    f16x4 hv = {(f16)uv.x, (f16)uv.y, (f16)uv.z, (f16)uv.w};
    *(f16x4*)&U[col * 64 + ((j >> 3) ^ (col & 7)) * 8 + (j & 7)] = hv;
  }
  asm volatile("s_waitcnt vmcnt(0)" ::: "memory");
  __syncthreads();

  // ---- MFMA1: L = V · u  (M=64 st, N=64 cols, K=64) ----
  const int col = wid * 16 + (lane & 15);
  f32x4 acc[4];
#pragma unroll
  for (int i = 0; i < 4; ++i) acc[i] = (f32x4){0.f, 0.f, 0.f, 0.f};
#pragma unroll
  for (int ks = 0; ks < 2; ++ks) {
    const int kc = ks * 4 + (lane >> 4);
    f16x8 bv = *(const f16x8*)&U[col * 64 + ((kc ^ (col & 7)) * 8)];
#pragma unroll
    for (int mf = 0; mf < 4; ++mf) {
      int row = mf * 16 + (lane & 15);
      f16x8 a = *(const f16x8*)&MATS[row * 64 + ((kc ^ (row & 7)) * 8)];
      acc[mf] = __builtin_amdgcn_mfma_f32_16x16x32_f16(a, bv, acc[mf], 0, 0, 0);
    }
  }
  __syncthreads();   // V reads drained; safe to overwrite MATS

  // issue A3 loads (hide under L-write + scan)
#pragma unroll
  for (int q = 0; q < 4; ++q)
    __builtin_amdgcn_global_load_lds((const gvoid*)(A3g + (size_t)h * 8192 + (q * 256 + tid) * 8),
                                     (lvoid*)&MATS[(q * 256 + wid * 64) * 8], 16, 0, 0);

  // write L frags to LE: [col][st] chunk^(col&7)
#pragma unroll
  for (int mf = 0; mf < 4; ++mf) {
    int st0 = mf * 16 + (lane >> 4) * 4;
    f16x4 o = {(f16)acc[mf][0], (f16)acc[mf][1], (f16)acc[mf][2], (f16)acc[mf][3]};
    *(f16x4*)&LE[col * 64 + (((st0 >> 3) ^ (col & 7)) << 3) + (st0 & 7)] = o;
  }
  __syncthreads();

  // ---- in-LDS scan over 64 blocks; 32 lanes (n = tid), batched 8-ahead ----
  if (tid < 32) {
    const int n = tid;
    const float2 wT = w64g[h * 32 + n];
    float er = 0.f, ei = 0.f;
#pragma unroll
    for (int g = 0; g < 8; ++g) {
      f16x2 Lb[8];
#pragma unroll
      for (int k = 0; k < 8; ++k) {
        int blk = g * 8 + k;
        int fi = blk * 64 + (((n >> 2) ^ (blk & 7)) << 3) + ((n & 3) << 1);
        Lb[k] = *(const f16x2*)&LE[fi];
      }
#pragma unroll
      for (int k = 0; k < 8; ++k) {
        int blk = g * 8 + k;
        int fi = blk * 64 + (((n >> 2) ^ (blk & 7)) << 3) + ((n & 3) << 1);
        *(f16x2*)&LE[fi] = (f16x2){(f16)er, (f16)ei};
        float nr = fmaf(wT.x, er, fmaf(-wT.y, ei, (float)Lb[k][0]));
        float ni = fmaf(wT.y, er, fmaf(wT.x, ei, (float)Lb[k][1]));
        er = nr; ei = ni;
      }
    }
  }
  asm volatile("s_waitcnt vmcnt(0)" ::: "memory");   // own A3 loads done
  __syncthreads();                                    // everyone's A3 + E visible

  // ---- y-GEMM: A = A3 (MATS 64x128), B = [U | LE] read in place ----
  f32x4 acc4[4];
#pragma unroll
  for (int i = 0; i < 4; ++i) acc4[i] = (f32x4){0.f, 0.f, 0.f, 0.f};
#pragma unroll
  for (int ks = 0; ks < 4; ++ks) {
    const int kc = ks * 4 + (lane >> 4);   // 0..15, uniform half per ks
    f16x8 bf;
    if (ks < 2) bf = *(const f16x8*)&U[col * 64 + ((kc ^ (col & 7)) << 3)];
    else        bf = *(const f16x8*)&LE[col * 64 + (((kc - 8) ^ (col & 7)) << 3)];
#pragma unroll
    for (int mf = 0; mf < 4; ++mf) {
      int row = mf * 16 + (lane & 15);
      f16x8 af = *(const f16x8*)&MATS[row * 128 + ((kc ^ (row & 7)) << 3)];
      acc4[mf] = __builtin_amdgcn_mfma_f32_16x16x32_f16(af, bf, acc4[mf], 0, 0, 0);
    }
  }
  // epilogue: v = y + D*u; exact GELU; direct f16x4 stores
  const int t0 = (lane >> 4) * 4;
#pragma unroll
  for (int mf = 0; mf < 4; ++mf) {
    const int tb = mf * 16 + t0;
    f16x4 uq = *(const f16x4*)&U[col * 64 + (((tb >> 3) ^ (col & 7)) << 3) + (tb & 7)];
    f16x4 o;
#pragma unroll
    for (int r = 0; r < 4; ++r) {
      float v = acc4[mf][r] + Dh * (float)uq[r];
      o[r] = (f16)(0.5f * v * (1.0f + erff(v * 0.70710678118654752f)));
    }
    *(f16x4*)&yg[((size_t)(b * Hn + h)) * Ln + col * 64 + tb] = o;
  }
}

// ============ K5: transpose y[b][h][l] -> gyT[b][l][h] ============
__global__ __launch_bounds__(256) void k_transpose(
    const f16* __restrict__ yg, f16* __restrict__ gyT) {
  __shared__ float T[64][65];
  const int bid = blockIdx.x, tid = threadIdx.x;
  const int b = bid >> 9, hg = (bid >> 6) & 7, lg = bid & 63;
  const int h0 = hg * 64, l0 = lg * 64;
  const int hi = tid >> 2, lc = (tid & 3) * 16;
  const f16* src = yg + ((size_t)(b * Hn + h0 + hi)) * Ln + l0 + lc;
  f16x8 v0 = *(const f16x8*)src;
  f16x8 v1 = *(const f16x8*)(src + 8);
#pragma unroll
  for (int e = 0; e < 8; ++e) T[lc + e][hi] = (float)v0[e];
#pragma unroll
  for (int e = 0; e < 8; ++e) T[lc + 8 + e][hi] = (float)v1[e];
  __syncthreads();
  const int li = tid >> 2, hc = (tid & 3) * 16;
  f16x8 o0, o1;
#pragma unroll
  for (int e = 0; e < 8; ++e) o0[e] = (f16)T[li][hc + e];
#pragma unroll
  for (int e = 0; e < 8; ++e) o1[e] = (f16)T[li][hc + 8 + e];
  f16* dst = gyT + ((size_t)b * Ln + l0 + li) * Hn + h0 + hc;
  *(f16x8*)dst = o0;
  *(f16x8*)(dst + 8) = o1;
}

// ============ K6: dual GEMM (a,g) + bias + GLU — swizzled LDS ============
__global__ __launch_bounds__(256, 2) void s4d_gemm(
    const f16* __restrict__ Wh, const f16* __restrict__ gyT,
    const float* __restrict__ bias, float* __restrict__ out) {
  __shared__ f16 As[2][128][64];
  __shared__ f16 Bs[128][64];
  const int tid = threadIdx.x;
  const int wid = tid >> 6, lane = tid & 63;
  const int ntg = blockIdx.x & 255;
  const int mt = blockIdx.x >> 8;
  const int b = ntg >> 5;
  const int l0 = (ntg & 31) * 128;
  const int m0 = mt * 128;
  const int wm = wid >> 1, wn = wid & 1;

  f32x4 acc[2][4][4];
#pragma unroll
  for (int a = 0; a < 2; ++a)
#pragma unroll
    for (int i = 0; i < 4; ++i)
#pragma unroll
      for (int j = 0; j < 4; ++j) acc[a][i][j] = (f32x4){0.f, 0.f, 0.f, 0.f};

  const int srow = lane >> 3;              // row within 8-row group
  const int sks = ((lane & 7) ^ srow) * 8; // inverse-swizzled source k-offset

  for (int kt = 0; kt < 8; ++kt) {
    const int k0 = kt * 64;
#pragma unroll
    for (int q = 0; q < 4; ++q) {
      const int r8 = wid * 32 + q * 8;
      const f16* srcA = Wh + ((size_t)(m0 + r8 + srow) * 512 + k0 + sks);
      __builtin_amdgcn_global_load_lds((const gvoid*)srcA, (lvoid*)&As[0][r8][0], 16, 0, 0);
      const f16* srcG = Wh + ((size_t)(Hn + m0 + r8 + srow) * 512 + k0 + sks);
      __builtin_amdgcn_global_load_lds((const gvoid*)srcG, (lvoid*)&As[1][r8][0], 16, 0, 0);
      const f16* srcB = gyT + (((size_t)b * Ln + l0 + r8 + srow) * Hn + k0 + sks);
      __builtin_amdgcn_global_load_lds((const gvoid*)srcB, (lvoid*)&Bs[r8][0], 16, 0, 0);
    }
    asm volatile("s_waitcnt vmcnt(0)" ::: "memory");
    __syncthreads();
#pragma unroll
    for (int kk = 0; kk < 2; ++kk) {
      const int kc = kk * 4 + (lane >> 4);   // logical k-chunk
      f16x8 af0[4], af1[4], bfv[4];
#pragma unroll
      for (int mf = 0; mf < 4; ++mf) {
        const int row = wm * 64 + mf * 16 + (lane & 15);
        af0[mf] = *(const f16x8*)&As[0][row][(kc ^ (row & 7)) * 8];
        af1[mf] = *(const f16x8*)&As[1][row][(kc ^ (row & 7)) * 8];
      }
#pragma unroll
      for (int nf = 0; nf < 4; ++nf) {
        const int col = wn * 64 + nf * 16 + (lane & 15);
        bfv[nf] = *(const f16x8*)&Bs[col][(kc ^ (col & 7)) * 8];
      }
#pragma unroll
      for (int mf = 0; mf < 4; ++mf)
#pragma unroll
        for (int nf = 0; nf < 4; ++nf) {
          acc[0][mf][nf] = __builtin_amdgcn_mfma_f32_16x16x32_f16(af0[mf], bfv[nf], acc[0][mf][nf], 0, 0, 0);
          acc[1][mf][nf] = __builtin_amdgcn_mfma_f32_16x16x32_f16(af1[mf], bfv[nf], acc[1][mf][nf], 0, 0, 0);
        }
    }
    __syncthreads();
  }

  const int col = lane & 15, r0 = (lane >> 4) * 4;
#pragma unroll
  for (int mf = 0; mf < 4; ++mf) {
    const int hbase = m0 + wm * 64 + mf * 16 + r0;
#pragma unroll
    for (int nf = 0; nf < 4; ++nf) {
      const int l = l0 + wn * 64 + nf * 16 + col;
      f32x4 va = acc[0][mf][nf], vg = acc[1][mf][nf];
#pragma unroll
      for (int r = 0; r < 4; ++r) {
        const int hh = hbase + r;
        float av = va[r] + bias[hh];
        float gv = vg[r] + bias[Hn + hh];
        float sg = __builtin_amdgcn_rcpf(1.0f + __expf(-gv));
        out[((size_t)b * Hn + hh) * Ln + l] = av * sg;
      }
    }
  }
}

extern "C" void kernel_launch(void* const* d_in, const int* in_sizes, int n_in,
                              void* d_out, int out_size, void* d_ws, size_t ws_size,
                              hipStream_t stream) {
  (void)in_sizes; (void)n_in; (void)out_size; (void)ws_size;
  const float* u     = (const float*)d_in[0];
  const float* C     = (const float*)d_in[1];
  const float* logdt = (const float*)d_in[2];
  const float* logA  = (const float*)d_in[3];
  const float* Aim   = (const float*)d_in[4];
  const float* Dv    = (const float*)d_in[5];
  const float* W     = (const float*)d_in[6];
  const float* bias  = (const float*)d_in[7];
  float* out = (float*)d_out;

  char* ws = (char*)d_ws;
  f16*    gyT  = (f16*)ws;                                  // 32 MB
  f16*    Vg   = (f16*)(ws + (size_t)(32 << 20));           // 4 MB
  f16*    A3g  = (f16*)(ws + (size_t)(36 << 20));           // 8 MB
  float2* w64g = (float2*)(ws + (size_t)(44 << 20));        // 128 KB
  f16*    Wh   = (f16*)(ws + (size_t)(45 << 20));           // 1 MB
  f16*    yg   = (f16*)d_out;                               // dead before K6 writes

  hipLaunchKernelGGL(k_mats1, dim3(Hn), dim3(64), 0, stream, C, logdt, logA, Aim, Vg, A3g, w64g);
  hipLaunchKernelGGL(conv_w, dim3(2048), dim3(256), 0, stream, W, Wh);
  hipLaunchKernelGGL(s4d_mid, dim3(Hn * Bn), dim3(256), 0, stream, u, Vg, A3g, w64g, Dv, yg);
  hipLaunchKernelGGL(k_transpose, dim3(Bn * 8 * 64), dim3(256), 0, stream, yg, gyT);
  hipLaunchKernelGGL(s4d_gemm, dim3(4 * 256), dim3(256), 0, stream, Wh, gyT, bias, out);
}

// Round 9
// 97.912 us; speedup vs baseline: 2.5407x; 1.1485x over previous
//
#include <hip/hip_runtime.h>
#include <hip/hip_bf16.h>

constexpr int Bn = 8, Hn = 512, Ln = 4096, N2n = 32;

typedef _Float16 f16;
typedef __attribute__((ext_vector_type(8))) _Float16 f16x8;
typedef __attribute__((ext_vector_type(4))) _Float16 f16x4;
typedef __attribute__((ext_vector_type(2))) _Float16 f16x2;
typedef __attribute__((ext_vector_type(4))) float f32x4;

typedef void __attribute__((address_space(1))) gvoid;
typedef void __attribute__((address_space(3))) lvoid;

// ============ K0: per-h param matrices (V, full A3 incl Toeplitz, w64) ============
__global__ __launch_bounds__(64) void k_mats1(
    const float* __restrict__ C, const float* __restrict__ log_dt,
    const float* __restrict__ logA, const float* __restrict__ Aim,
    f16* __restrict__ Vg, f16* __restrict__ A3g, float2* __restrict__ w64g) {
  __shared__ f16 VT[64 * 64];
  __shared__ f16 QT[64 * 64];
  __shared__ float kp[64][33];
  __shared__ float ks[64];
  const int h = blockIdx.x, tid = threadIdx.x, n = tid & 31;

  if (tid < 32) {
    const int idx = h * N2n + n;
    float dt = expf(log_dt[h]);
    float Ar = -expf(logA[idx]);
    float Ai = Aim[idx];
    float dr = Ar * dt, di = Ai * dt;
    float er = expf(dr);
    float wr = er * cosf(di), wi = er * sinf(di);
    float den = Ar * Ar + Ai * Ai;
    float e1r = wr - 1.0f, e1i = wi;
    float tr = (e1r * Ar + e1i * Ai) / den;
    float ti = (e1i * Ar - e1r * Ai) / den;
    float Cr = C[idx * 2 + 0], Ci = C[idx * 2 + 1];
    float c2r = 2.0f * (Cr * tr - Ci * ti);
    float c2i = 2.0f * (Cr * ti + Ci * tr);

    float wpr = 1.f, wpi = 0.f;   // w^p
    for (int p = 0; p <= 64; ++p) {
      float cwr = c2r * wpr - c2i * wpi;   // C2 * w^p
      float cwi = c2r * wpi + c2i * wpr;
      if (p < 64) {
        const int j = 63 - p, ch = j >> 3, jo = j & 7;
        const int s0 = 2 * n, s1 = 2 * n + 1;
        VT[s0 * 64 + ((ch ^ (s0 & 7)) * 8) + jo] = (f16)wpr;
        VT[s1 * 64 + ((ch ^ (s1 & 7)) * 8) + jo] = (f16)wpi;
        kp[p][n] = cwr;
      }
      if (p >= 1) {
        const int t = p - 1, c0 = 2 * n;
        const int ch = (c0 >> 3) ^ (t & 7);
        QT[t * 64 + ch * 8 + (c0 & 7)]     = (f16)cwr;
        QT[t * 64 + ch * 8 + (c0 & 7) + 1] = (f16)(-cwi);
      }
      if (p == 64) w64g[h * 32 + n] = make_float2(wpr, wpi);
      float nr = wpr * wr - wpi * wi;
      float ni = wpr * wi + wpi * wr;
      wpr = nr; wpi = ni;
    }
  }
  __syncthreads();
  float s = 0.f;
#pragma unroll
  for (int m = 0; m < 32; ++m) s += kp[tid][m];
  ks[tid] = s;
  __syncthreads();
  const int t = tid;
#pragma unroll
  for (int c = 0; c < 8; ++c) {
    f16x8 row;
#pragma unroll
    for (int jo = 0; jo < 8; ++jo) {
      int j = c * 8 + jo;
      row[jo] = (j <= t) ? (f16)ks[t - j] : (f16)0.f;
    }
    *(f16x8*)&A3g[(size_t)h * 8192 + t * 128 + ((c ^ (t & 7)) * 8)] = row;
  }
#pragma unroll
  for (int c = 0; c < 8; ++c)
    *(f16x8*)&Vg[(size_t)h * 4096 + tid * 64 + c * 8] = *(f16x8*)&VT[tid * 64 + c * 8];
#pragma unroll
  for (int c = 0; c < 8; ++c)
    *(f16x8*)&A3g[(size_t)h * 8192 + tid * 128 + 64 + c * 8] = *(f16x8*)&QT[tid * 64 + c * 8];
}

// ============ K1: W fp32 -> f16 ============
__global__ void conv_w(const float* __restrict__ W, f16* __restrict__ Wh) {
  int i = blockIdx.x * 256 + threadIdx.x;
  if (i < 2 * Hn * Hn) Wh[i] = (f16)W[i];
}

// ============ K2: fused middle, one block per (h,b): ~33 KB LDS ============
// Grid remap: i%8 == h%8 so the 8 b-blocks of an h share one XCD's L2.
__global__ __launch_bounds__(256, 4) void s4d_mid(
    const float* __restrict__ u, const f16* __restrict__ Vg,
    const f16* __restrict__ A3g, const float2* __restrict__ w64g,
    const float* __restrict__ Dv, f16* __restrict__ yg) {
  __shared__ f16 MATS[8192];   // 16 KB: V in [0:4096), then A3 overwrites
  __shared__ f16 U[4096];      // 8 KB: [col=blk][j] chunk^(col&7)
  __shared__ f16 LE[4096];     // 8 KB: [col=blk][st] chunk^(col&7)
  __shared__ float2 Pbuf[4][32];  // 1 KB: quarter end-states
  const int tid = threadIdx.x, wid = tid >> 6, lane = tid & 63;
  const int h = ((blockIdx.x >> 6) << 3) | (blockIdx.x & 7);
  const int b = (blockIdx.x >> 3) & 7;
  const float Dh = Dv[h];

  // V -> MATS[0..4096)
#pragma unroll
  for (int q = 0; q < 2; ++q)
    __builtin_amdgcn_global_load_lds((const gvoid*)(Vg + (size_t)h * 4096 + (q * 256 + tid) * 8),
                                     (lvoid*)&MATS[(q * 256 + wid * 64) * 8], 16, 0, 0);
  // u staging (f32 -> f16), this batch only
#pragma unroll
  for (int i = 0; i < 4; ++i) {
    int e = (i * 256 + tid) * 4;          // 0..4095
    float4 uv = *(const float4*)(u + ((size_t)(b * Hn + h)) * Ln + e);
    int col = e >> 6, j = e & 63;
    f16x4 hv = {(f16)uv.x, (f16)uv.y, (f16)uv.z, (f16)uv.w};
    *(f16x4*)&U[col * 64 + ((j >> 3) ^ (col & 7)) * 8 + (j & 7)] = hv;
  }
  asm volatile("s_waitcnt vmcnt(0)" ::: "memory");
  __syncthreads();

  // ---- MFMA1: L = V · u  (M=64 st, N=64 cols, K=64) ----
  const int col = wid * 16 + (lane & 15);
  f32x4 acc[4];
#pragma unroll
  for (int i = 0; i < 4; ++i) acc[i] = (f32x4){0.f, 0.f, 0.f, 0.f};
#pragma unroll
  for (int ks = 0; ks < 2; ++ks) {
    const int kc = ks * 4 + (lane >> 4);
    f16x8 bv = *(const f16x8*)&U[col * 64 + ((kc ^ (col & 7)) * 8)];
#pragma unroll
    for (int mf = 0; mf < 4; ++mf) {
      int row = mf * 16 + (lane & 15);
      f16x8 a = *(const f16x8*)&MATS[row * 64 + ((kc ^ (row & 7)) * 8)];
      acc[mf] = __builtin_amdgcn_mfma_f32_16x16x32_f16(a, bv, acc[mf], 0, 0, 0);
    }
  }
  __syncthreads();   // V reads drained; safe to overwrite MATS

  // issue A3 loads (hide under L-write + scan)
#pragma unroll
  for (int q = 0; q < 4; ++q)
    __builtin_amdgcn_global_load_lds((const gvoid*)(A3g + (size_t)h * 8192 + (q * 256 + tid) * 8),
                                     (lvoid*)&MATS[(q * 256 + wid * 64) * 8], 16, 0, 0);

  // write L frags to LE: [col][st] chunk^(col&7)
#pragma unroll
  for (int mf = 0; mf < 4; ++mf) {
    int st0 = mf * 16 + (lane >> 4) * 4;
    f16x4 o = {(f16)acc[mf][0], (f16)acc[mf][1], (f16)acc[mf][2], (f16)acc[mf][3]};
    *(f16x4*)&LE[col * 64 + (((st0 >> 3) ^ (col & 7)) << 3) + (st0 & 7)] = o;
  }
  __syncthreads();

  // ---- parallel in-LDS scan: wave q handles blocks 16q..16q+15 (lanes 0..31) ----
  {
    const int n = lane & 31, q = wid;
    const float2 wT = w64g[h * 32 + n];
    // w1024 = w64^16 via 4 complex squarings
    float qr = wT.x, qi = wT.y;
#pragma unroll
    for (int s = 0; s < 4; ++s) {
      float nr = qr * qr - qi * qi;
      float ni = 2.f * qr * qi;
      qr = nr; qi = ni;
    }
    f16x2 Lb[16];
    float er = 0.f, ei = 0.f;
    if (lane < 32) {
#pragma unroll
      for (int k = 0; k < 16; ++k) {
        int blk = q * 16 + k;
        int fi = blk * 64 + (((n >> 2) ^ (blk & 7)) << 3) + ((n & 3) << 1);
        Lb[k] = *(const f16x2*)&LE[fi];
      }
#pragma unroll
      for (int k = 0; k < 16; ++k) {   // local scan from zero
        float nr = fmaf(wT.x, er, fmaf(-wT.y, ei, (float)Lb[k][0]));
        float ni = fmaf(wT.y, er, fmaf(wT.x, ei, (float)Lb[k][1]));
        er = nr; ei = ni;
      }
      Pbuf[q][n] = make_float2(er, ei);
    }
    __syncthreads();
    if (lane < 32) {
      float orr = 0.f, oii = 0.f;
      for (int p = 0; p < q; ++p) {    // wave-uniform trip count
        float2 Pp = Pbuf[p][n];
        float nr = fmaf(qr, orr, fmaf(-qi, oii, Pp.x));
        float ni = fmaf(qi, orr, fmaf(qr, oii, Pp.y));
        orr = nr; oii = ni;
      }
      er = orr; ei = oii;              // state entering block 16q
#pragma unroll
      for (int k = 0; k < 16; ++k) {
        int blk = q * 16 + k;
        int fi = blk * 64 + (((n >> 2) ^ (blk & 7)) << 3) + ((n & 3) << 1);
        *(f16x2*)&LE[fi] = (f16x2){(f16)er, (f16)ei};
        float nr = fmaf(wT.x, er, fmaf(-wT.y, ei, (float)Lb[k][0]));
        float ni = fmaf(wT.y, er, fmaf(wT.x, ei, (float)Lb[k][1]));
        er = nr; ei = ni;
      }
    }
  }
  asm volatile("s_waitcnt vmcnt(0)" ::: "memory");   // own A3 loads done
  __syncthreads();                                    // everyone's A3 + E visible

  // ---- y-GEMM: A = A3 (MATS 64x128), B = [U | LE] read in place ----
  f32x4 acc4[4];
#pragma unroll
  for (int i = 0; i < 4; ++i) acc4[i] = (f32x4){0.f, 0.f, 0.f, 0.f};
#pragma unroll
  for (int ks = 0; ks < 4; ++ks) {
    const int kc = ks * 4 + (lane >> 4);   // 0..15, uniform half per ks
    f16x8 bf;
    if (ks < 2) bf = *(const f16x8*)&U[col * 64 + ((kc ^ (col & 7)) << 3)];
    else        bf = *(const f16x8*)&LE[col * 64 + (((kc - 8) ^ (col & 7)) << 3)];
#pragma unroll
    for (int mf = 0; mf < 4; ++mf) {
      int row = mf * 16 + (lane & 15);
      f16x8 af = *(const f16x8*)&MATS[row * 128 + ((kc ^ (row & 7)) << 3)];
      acc4[mf] = __builtin_amdgcn_mfma_f32_16x16x32_f16(af, bf, acc4[mf], 0, 0, 0);
    }
  }
  // epilogue: v = y + D*u; tanh-GELU (exp+rcp); direct f16x4 stores
  const int t0 = (lane >> 4) * 4;
#pragma unroll
  for (int mf = 0; mf < 4; ++mf) {
    const int tb = mf * 16 + t0;
    f16x4 uq = *(const f16x4*)&U[col * 64 + (((tb >> 3) ^ (col & 7)) << 3) + (tb & 7)];
    f16x4 o;
#pragma unroll
    for (int r = 0; r < 4; ++r) {
      float v = acc4[mf][r] + Dh * (float)uq[r];
      float g2 = v * fmaf(0.0713548163f, v * v, 1.5957691216f);
      o[r] = (f16)(v * __builtin_amdgcn_rcpf(1.0f + __expf(-g2)));
    }
    *(f16x4*)&yg[((size_t)(b * Hn + h)) * Ln + col * 64 + tb] = o;
  }
}

// ============ K5: transpose y[b][h][l] -> gyT[b][l][h] ============
__global__ __launch_bounds__(256) void k_transpose(
    const f16* __restrict__ yg, f16* __restrict__ gyT) {
  __shared__ float T[64][65];
  const int bid = blockIdx.x, tid = threadIdx.x;
  const int b = bid >> 9, hg = (bid >> 6) & 7, lg = bid & 63;
  const int h0 = hg * 64, l0 = lg * 64;
  const int hi = tid >> 2, lc = (tid & 3) * 16;
  const f16* src = yg + ((size_t)(b * Hn + h0 + hi)) * Ln + l0 + lc;
  f16x8 v0 = *(const f16x8*)src;
  f16x8 v1 = *(const f16x8*)(src + 8);
#pragma unroll
  for (int e = 0; e < 8; ++e) T[lc + e][hi] = (float)v0[e];
#pragma unroll
  for (int e = 0; e < 8; ++e) T[lc + 8 + e][hi] = (float)v1[e];
  __syncthreads();
  const int li = tid >> 2, hc = (tid & 3) * 16;
  f16x8 o0, o1;
#pragma unroll
  for (int e = 0; e < 8; ++e) o0[e] = (f16)T[li][hc + e];
#pragma unroll
  for (int e = 0; e < 8; ++e) o1[e] = (f16)T[li][hc + 8 + e];
  f16* dst = gyT + ((size_t)b * Ln + l0 + li) * Hn + h0 + hc;
  *(f16x8*)dst = o0;
  *(f16x8*)(dst + 8) = o1;
}

// ============ K6: dual GEMM (a,g) + bias + GLU — swizzled LDS ============
__global__ __launch_bounds__(256, 2) void s4d_gemm(
    const f16* __restrict__ Wh, const f16* __restrict__ gyT,
    const float* __restrict__ bias, float* __restrict__ out) {
  __shared__ f16 As[2][128][64];
  __shared__ f16 Bs[128][64];
  const int tid = threadIdx.x;
  const int wid = tid >> 6, lane = tid & 63;
  const int ntg = blockIdx.x & 255;
  const int mt = blockIdx.x >> 8;
  const int b = ntg >> 5;
  const int l0 = (ntg & 31) * 128;
  const int m0 = mt * 128;
  const int wm = wid >> 1, wn = wid & 1;

  f32x4 acc[2][4][4];
#pragma unroll
  for (int a = 0; a < 2; ++a)
#pragma unroll
    for (int i = 0; i < 4; ++i)
#pragma unroll
      for (int j = 0; j < 4; ++j) acc[a][i][j] = (f32x4){0.f, 0.f, 0.f, 0.f};

  const int srow = lane >> 3;              // row within 8-row group
  const int sks = ((lane & 7) ^ srow) * 8; // inverse-swizzled source k-offset

  for (int kt = 0; kt < 8; ++kt) {
    const int k0 = kt * 64;
#pragma unroll
    for (int q = 0; q < 4; ++q) {
      const int r8 = wid * 32 + q * 8;
      const f16* srcA = Wh + ((size_t)(m0 + r8 + srow) * 512 + k0 + sks);
      __builtin_amdgcn_global_load_lds((const gvoid*)srcA, (lvoid*)&As[0][r8][0], 16, 0, 0);
      const f16* srcG = Wh + ((size_t)(Hn + m0 + r8 + srow) * 512 + k0 + sks);
      __builtin_amdgcn_global_load_lds((const gvoid*)srcG, (lvoid*)&As[1][r8][0], 16, 0, 0);
      const f16* srcB = gyT + (((size_t)b * Ln + l0 + r8 + srow) * Hn + k0 + sks);
      __builtin_amdgcn_global_load_lds((const gvoid*)srcB, (lvoid*)&Bs[r8][0], 16, 0, 0);
    }
    asm volatile("s_waitcnt vmcnt(0)" ::: "memory");
    __syncthreads();
#pragma unroll
    for (int kk = 0; kk < 2; ++kk) {
      const int kc = kk * 4 + (lane >> 4);   // logical k-chunk
      f16x8 af0[4], af1[4], bfv[4];
#pragma unroll
      for (int mf = 0; mf < 4; ++mf) {
        const int row = wm * 64 + mf * 16 + (lane & 15);
        af0[mf] = *(const f16x8*)&As[0][row][(kc ^ (row & 7)) * 8];
        af1[mf] = *(const f16x8*)&As[1][row][(kc ^ (row & 7)) * 8];
      }
#pragma unroll
      for (int nf = 0; nf < 4; ++nf) {
        const int col = wn * 64 + nf * 16 + (lane & 15);
        bfv[nf] = *(const f16x8*)&Bs[col][(kc ^ (col & 7)) * 8];
      }
#pragma unroll
      for (int mf = 0; mf < 4; ++mf)
#pragma unroll
        for (int nf = 0; nf < 4; ++nf) {
          acc[0][mf][nf] = __builtin_amdgcn_mfma_f32_16x16x32_f16(af0[mf], bfv[nf], acc[0][mf][nf], 0, 0, 0);
          acc[1][mf][nf] = __builtin_amdgcn_mfma_f32_16x16x32_f16(af1[mf], bfv[nf], acc[1][mf][nf], 0, 0, 0);
        }
    }
    __syncthreads();
  }

  const int col = lane & 15, r0 = (lane >> 4) * 4;
#pragma unroll
  for (int mf = 0; mf < 4; ++mf) {
    const int hbase = m0 + wm * 64 + mf * 16 + r0;
#pragma unroll
    for (int nf = 0; nf < 4; ++nf) {
      const int l = l0 + wn * 64 + nf * 16 + col;
      f32x4 va = acc[0][mf][nf], vg = acc[1][mf][nf];
#pragma unroll
      for (int r = 0; r < 4; ++r) {
        const int hh = hbase + r;
        float av = va[r] + bias[hh];
        float gv = vg[r] + bias[Hn + hh];
        float sg = __builtin_amdgcn_rcpf(1.0f + __expf(-gv));
        out[((size_t)b * Hn + hh) * Ln + l] = av * sg;
      }
    }
  }
}

extern "C" void kernel_launch(void* const* d_in, const int* in_sizes, int n_in,
                              void* d_out, int out_size, void* d_ws, size_t ws_size,
                              hipStream_t stream) {
  (void)in_sizes; (void)n_in; (void)out_size; (void)ws_size;
  const float* u     = (const float*)d_in[0];
  const float* C     = (const float*)d_in[1];
  const float* logdt = (const float*)d_in[2];
  const float* logA  = (const float*)d_in[3];
  const float* Aim   = (const float*)d_in[4];
  const float* Dv    = (const float*)d_in[5];
  const float* W     = (const float*)d_in[6];
  const float* bias  = (const float*)d_in[7];
  float* out = (float*)d_out;

  char* ws = (char*)d_ws;
  f16*    gyT  = (f16*)ws;                                  // 32 MB
  f16*    Vg   = (f16*)(ws + (size_t)(32 << 20));           // 4 MB
  f16*    A3g  = (f16*)(ws + (size_t)(36 << 20));           // 8 MB
  float2* w64g = (float2*)(ws + (size_t)(44 << 20));        // 128 KB
  f16*    Wh   = (f16*)(ws + (size_t)(45 << 20));           // 1 MB
  f16*    yg   = (f16*)d_out;                               // dead before K6 writes

  hipLaunchKernelGGL(k_mats1, dim3(Hn), dim3(64), 0, stream, C, logdt, logA, Aim, Vg, A3g, w64g);
  hipLaunchKernelGGL(conv_w, dim3(2048), dim3(256), 0, stream, W, Wh);
  hipLaunchKernelGGL(s4d_mid, dim3(Hn * Bn), dim3(256), 0, stream, u, Vg, A3g, w64g, Dv, yg);
  hipLaunchKernelGGL(k_transpose, dim3(Bn * 8 * 64), dim3(256), 0, stream, yg, gyT);
  hipLaunchKernelGGL(s4d_gemm, dim3(4 * 256), dim3(256), 0, stream, Wh, gyT, bias, out);
}